// Round 1
// baseline (9285.796 us; speedup 1.0000x reference)
//
#include <hip/hip_runtime.h>
#include <hip/hip_bf16.h>

#define B_ 32
#define L_ 512
#define D_ 768
#define DFF_ 3072
#define NL_ 2
#define TOPK_ 6
#define CMID_ 384
#define CLEN_ 510
#define PLEN_ 255
#define LATENT_ 32
#define NCELLS_ 2034
#define NROWS_ (B_*L_)
#define ND_ ((size_t)B_*L_*D_)

static __device__ __forceinline__ float geluf(float x) {
  return 0.5f * x * (1.f + erff(x * 0.70710678118654752440f));
}
static __device__ __forceinline__ float eluf(float x) {
  return x > 0.f ? x : expm1f(x);
}

// ---------------- embeddings ----------------
__global__ void embed_gather(const int* __restrict__ ids, const float* __restrict__ we,
                             const float* __restrict__ pe, const float* __restrict__ te,
                             float* __restrict__ x) {
  size_t stride = (size_t)gridDim.x * blockDim.x;
  for (size_t i = (size_t)blockIdx.x * blockDim.x + threadIdx.x; i < ND_; i += stride) {
    int d = (int)(i % D_);
    int row = (int)(i / D_);
    int t = row & (L_ - 1);
    int id = ids[row];
    x[i] = we[(size_t)id * D_ + d] + pe[(size_t)t * D_ + d] + te[d];
  }
}

// LayerNorm over last dim (768). One block per row, 256 threads x 3 elems.
__global__ __launch_bounds__(256) void ln_rows(const float* __restrict__ in, float* __restrict__ out,
                                               const float* __restrict__ g, const float* __restrict__ bta,
                                               float eps) {
  int row = blockIdx.x;
  int tid = threadIdx.x;
  const float* r = in + (size_t)row * D_;
  float v0 = r[tid], v1 = r[tid + 256], v2 = r[tid + 512];
  float s = v0 + v1 + v2;
  float sq = v0 * v0 + v1 * v1 + v2 * v2;
  __shared__ float rs[256], rq[256];
  rs[tid] = s; rq[tid] = sq;
  __syncthreads();
  for (int st = 128; st > 0; st >>= 1) {
    if (tid < st) { rs[tid] += rs[tid + st]; rq[tid] += rq[tid + st]; }
    __syncthreads();
  }
  __shared__ float smu, ssc;
  if (tid == 0) {
    float mu = rs[0] * (1.f / D_);
    float var = fmaxf(rq[0] * (1.f / D_) - mu * mu, 0.f);
    smu = mu; ssc = rsqrtf(var + eps);
  }
  __syncthreads();
  float mu = smu, sc = ssc;
  float* o = out + (size_t)row * D_;
  o[tid]       = (v0 - mu) * sc * g[tid]       + bta[tid];
  o[tid + 256] = (v1 - mu) * sc * g[tid + 256] + bta[tid + 256];
  o[tid + 512] = (v2 - mu) * sc * g[tid + 512] + bta[tid + 512];
}

// ---------------- GEMM: C[m,o] = act(sum_k A[m,k]*W[o,k] + bias[o]) ----------------
// A: [M,K] rm, W: [O,K] rm (NT). M,O multiples of 128, K multiple of 16.
#define BM 128
#define BN 128
#define BKK 16
template<int ACT>
__global__ __launch_bounds__(256) void gemm_nt(const float* __restrict__ A, const float* __restrict__ W,
                                               const float* __restrict__ bias, float* __restrict__ C,
                                               int M, int O, int K) {
  __shared__ float As[BKK][BM + 4];
  __shared__ float Ws[BKK][BN + 4];
  int m0 = blockIdx.y * BM, o0 = blockIdx.x * BN;
  int tid = threadIdx.x;
  int tx = tid & 15, ty = tid >> 4;
  float acc[8][8] = {};
  for (int k0 = 0; k0 < K; k0 += BKK) {
#pragma unroll
    for (int i = 0; i < 2; i++) {
      int idx = tid + i * 256;
      int row = idx >> 2;
      int c4 = (idx & 3) * 4;
      const float4 av = *(const float4*)(A + (size_t)(m0 + row) * K + k0 + c4);
      As[c4 + 0][row] = av.x; As[c4 + 1][row] = av.y; As[c4 + 2][row] = av.z; As[c4 + 3][row] = av.w;
      const float4 wv = *(const float4*)(W + (size_t)(o0 + row) * K + k0 + c4);
      Ws[c4 + 0][row] = wv.x; Ws[c4 + 1][row] = wv.y; Ws[c4 + 2][row] = wv.z; Ws[c4 + 3][row] = wv.w;
    }
    __syncthreads();
#pragma unroll
    for (int kk = 0; kk < BKK; kk++) {
      float4 a0 = *(const float4*)&As[kk][ty * 8];
      float4 a1 = *(const float4*)&As[kk][ty * 8 + 4];
      float4 w0 = *(const float4*)&Ws[kk][tx * 8];
      float4 w1 = *(const float4*)&Ws[kk][tx * 8 + 4];
      float a[8] = {a0.x, a0.y, a0.z, a0.w, a1.x, a1.y, a1.z, a1.w};
      float w[8] = {w0.x, w0.y, w0.z, w0.w, w1.x, w1.y, w1.z, w1.w};
#pragma unroll
      for (int i = 0; i < 8; i++)
#pragma unroll
        for (int j = 0; j < 8; j++)
          acc[i][j] = fmaf(a[i], w[j], acc[i][j]);
    }
    __syncthreads();
  }
#pragma unroll
  for (int i = 0; i < 8; i++) {
    int m = m0 + ty * 8 + i;
    float* crow = C + (size_t)m * O + o0 + tx * 8;
#pragma unroll
    for (int j = 0; j < 8; j++) {
      float v = acc[i][j] + bias[o0 + tx * 8 + j];
      if (ACT == 1) v = geluf(v);
      crow[j] = v;
    }
  }
}

// ---------------- autocorrelation mean: mv[b,tau] = (1/D) sum_t sum_d q[b,(t+tau)%L,d]*k[b,t,d] ----
__global__ __launch_bounds__(256) void autocorr_mean(const float* __restrict__ q, const float* __restrict__ k,
                                                     float* __restrict__ mv) {
  int blk = blockIdx.x;            // B * (L/8)
  int b = blk >> 6;
  int tau0 = (blk & 63) << 3;
  int tid = threadIdx.x;
  const float* qb = q + (size_t)b * L_ * D_;
  const float* kb = k + (size_t)b * L_ * D_;
  float acc[8] = {0, 0, 0, 0, 0, 0, 0, 0};
  for (int t = 0; t < L_; t++) {
    const float* krow = kb + (size_t)t * D_;
#pragma unroll
    for (int dd = 0; dd < 3; dd++) {
      int d = tid + dd * 256;
      float kv = krow[d];
#pragma unroll
      for (int j = 0; j < 8; j++) {
        int rr = (t + tau0 + j) & (L_ - 1);
        acc[j] = fmaf(qb[(size_t)rr * D_ + d], kv, acc[j]);
      }
    }
  }
  __shared__ float red[256];
  for (int j = 0; j < 8; j++) {
    red[tid] = acc[j];
    __syncthreads();
    for (int st = 128; st > 0; st >>= 1) {
      if (tid < st) red[tid] += red[tid + st];
      __syncthreads();
    }
    if (tid == 0) mv[(size_t)b * L_ + tau0 + j] = red[0] * (1.f / D_);
    __syncthreads();
  }
}

// ---------------- top-k(6) + softmax over delays ----------------
__global__ __launch_bounds__(256) void topk_softmax(const float* __restrict__ mv,
                                                    float* __restrict__ wout, int* __restrict__ dout) {
  int b = blockIdx.x, tid = threadIdx.x;
  __shared__ float vals[L_];
  __shared__ float rv[256];
  __shared__ int ri[256];
  __shared__ float wsel[TOPK_];
  __shared__ int dsel[TOPK_];
  vals[tid] = mv[(size_t)b * L_ + tid];
  vals[tid + 256] = mv[(size_t)b * L_ + tid + 256];
  for (int kk = 0; kk < TOPK_; kk++) {
    __syncthreads();
    float v0 = vals[tid], v1 = vals[tid + 256];
    float bvv = v0; int bi = tid;
    if (v1 > v0) { bvv = v1; bi = tid + 256; }
    rv[tid] = bvv; ri[tid] = bi;
    __syncthreads();
    for (int st = 128; st > 0; st >>= 1) {
      if (tid < st) {
        float ov = rv[tid + st]; int oi = ri[tid + st];
        if (ov > rv[tid] || (ov == rv[tid] && oi < ri[tid])) { rv[tid] = ov; ri[tid] = oi; }
      }
      __syncthreads();
    }
    if (tid == 0) { wsel[kk] = rv[0]; dsel[kk] = ri[0]; vals[ri[0]] = -INFINITY; }
  }
  __syncthreads();
  if (tid == 0) {
    float mx = wsel[0];
    for (int i = 1; i < TOPK_; i++) mx = fmaxf(mx, wsel[i]);
    float e[TOPK_]; float sum = 0.f;
    for (int i = 0; i < TOPK_; i++) { e[i] = expf(wsel[i] - mx); sum += e[i]; }
    for (int i = 0; i < TOPK_; i++) { wout[b * TOPK_ + i] = e[i] / sum; dout[b * TOPK_ + i] = dsel[i]; }
  }
}

// out[b,t,d] = sum_k w[b,k] * v[b,(t+delay[b,k])%L,d]
__global__ __launch_bounds__(256) void agg_v(const float* __restrict__ v, const float* __restrict__ w,
                                             const int* __restrict__ dly, float* __restrict__ out) {
  int blr = blockIdx.x;      // b*L + t
  int b = blr >> 9, t = blr & 511;
  int tid = threadIdx.x;
  __shared__ float ww[TOPK_];
  __shared__ int rr[TOPK_];
  if (tid < TOPK_) { ww[tid] = w[b * TOPK_ + tid]; rr[tid] = (t + dly[b * TOPK_ + tid]) & (L_ - 1); }
  __syncthreads();
  const float* vb = v + (size_t)b * L_ * D_;
#pragma unroll
  for (int dd = 0; dd < 3; dd++) {
    int d = tid + dd * 256;
    float s = 0.f;
#pragma unroll
    for (int kk = 0; kk < TOPK_; kk++) s = fmaf(ww[kk], vb[(size_t)rr[kk] * D_ + d], s);
    out[(size_t)blr * D_ + d] = s;
  }
}

__global__ void add_vec(const float* __restrict__ a, const float* __restrict__ b,
                        float* __restrict__ o, size_t n) {
  size_t stride = (size_t)gridDim.x * blockDim.x;
  for (size_t i = (size_t)blockIdx.x * blockDim.x + threadIdx.x; i < n; i += stride)
    o[i] = a[i] + b[i];
}

// out = s - movavg25(s) with replicate padding; thread owns a (b,d,chunk-of-128) column segment
__global__ void decomp_k(const float* __restrict__ s, float* __restrict__ out) {
  int gid = blockIdx.x * blockDim.x + threadIdx.x;   // B*4*D
  if (gid >= B_ * 4 * D_) return;
  int d = gid % D_;
  int chunk = (gid / D_) & 3;
  int b = gid / (D_ * 4);
  const float* col = s + (size_t)b * L_ * D_ + d;
  float* ocol = out + (size_t)b * L_ * D_ + d;
  int t0 = chunk * 128;
  float wsum = 0.f;
  for (int u = t0 - 12; u <= t0 + 12; u++) {
    int uc = u < 0 ? 0 : (u > L_ - 1 ? L_ - 1 : u);
    wsum += col[(size_t)uc * D_];
  }
  for (int t = t0; t < t0 + 128; t++) {
    ocol[(size_t)t * D_] = col[(size_t)t * D_] - wsum * (1.f / 25.f);
    int ua = t + 13 > L_ - 1 ? L_ - 1 : t + 13;
    int ur = t - 12 < 0 ? 0 : t - 12;
    wsum += col[(size_t)ua * D_] - col[(size_t)ur * D_];
  }
}

// x[b,:,d] -= mean_t x[b,:,d]  (in place)
__global__ void colmean_sub(float* __restrict__ x) {
  int gid = blockIdx.x * blockDim.x + threadIdx.x;   // B*D
  if (gid >= B_ * D_) return;
  int d = gid % D_, b = gid / D_;
  float* col = x + (size_t)b * L_ * D_ + d;
  float s = 0.f;
  for (int t = 0; t < L_; t++) s += col[(size_t)t * D_];
  float mu = s * (1.f / L_);
  for (int t = 0; t < L_; t++) col[(size_t)t * D_] -= mu;
}

// conv1d k=3 VALID over t: c[b,o,t] = sum_{i,j} att[b,t+j,i]*W[o,i,j] + bias[o]
#define TCH 15
__global__ __launch_bounds__(384) void conv1d_k(const float* __restrict__ att, const float* __restrict__ W,
                                                const float* __restrict__ bias, float* __restrict__ out) {
  __shared__ float lds[(TCH + 2) * D_];
  int b = blockIdx.y;
  int t0 = blockIdx.x * TCH;
  int tid = threadIdx.x;
  for (int idx = tid; idx < (TCH + 2) * D_; idx += 384) {
    int r = idx / D_, c = idx % D_;
    lds[idx] = att[((size_t)b * L_ + t0 + r) * D_ + c];
  }
  __syncthreads();
  int o = tid;   // 384 threads = CMID
  float acc[TCH] = {};
  const float* wo = W + (size_t)o * D_ * 3;
  for (int i = 0; i < D_; i++) {
    float w0 = wo[i * 3 + 0], w1 = wo[i * 3 + 1], w2 = wo[i * 3 + 2];
#pragma unroll
    for (int tt = 0; tt < TCH; tt++)
      acc[tt] += lds[tt * D_ + i] * w0 + lds[(tt + 1) * D_ + i] * w1 + lds[(tt + 2) * D_ + i] * w2;
  }
  float bvv = bias[o];
  for (int tt = 0; tt < TCH; tt++)
    out[((size_t)b * CMID_ + o) * CLEN_ + t0 + tt] = acc[tt] + bvv;
}

__global__ void bn_elu_pool(const float* __restrict__ c, const float* __restrict__ bm,
                            const float* __restrict__ bvv, const float* __restrict__ bg,
                            const float* __restrict__ bb, float* __restrict__ f) {
  int gid = blockIdx.x * blockDim.x + threadIdx.x;
  if (gid >= B_ * CMID_ * PLEN_) return;
  int tp = gid % PLEN_;
  int o = (gid / PLEN_) % CMID_;
  int b = gid / (PLEN_ * CMID_);
  const float* base = c + ((size_t)b * CMID_ + o) * CLEN_ + 2 * tp;
  float sc = rsqrtf(bvv[o] + 1e-5f) * bg[o];
  float sh = bb[o] - bm[o] * sc;
  float x0 = eluf(base[0] * sc + sh);
  float x1 = eluf(base[1] * sc + sh);
  f[gid] = fmaxf(x0, x1);
}

__global__ __launch_bounds__(256) void lin1_k(const float* __restrict__ f, const float* __restrict__ w,
                                              const float* __restrict__ bias, float* __restrict__ out) {
  int o = blockIdx.x, b = blockIdx.y;
  int tid = threadIdx.x;
  const float4* fr = (const float4*)(f + (size_t)b * (CMID_ * PLEN_));
  const float4* wr = (const float4*)(w + (size_t)o * (CMID_ * PLEN_));
  const int n4 = CMID_ * PLEN_ / 4;
  float s = 0.f;
  for (int i = tid; i < n4; i += 256) {
    float4 a = fr[i], ww = wr[i];
    s += a.x * ww.x + a.y * ww.y + a.z * ww.z + a.w * ww.w;
  }
  __shared__ float red[256];
  red[tid] = s;
  __syncthreads();
  for (int st = 128; st > 0; st >>= 1) {
    if (tid < st) red[tid] += red[tid + st];
    __syncthreads();
  }
  if (tid == 0) out[b * LATENT_ + o] = red[0] + bias[o];
}

__global__ void ln_elu(const float* __restrict__ hp, const float* __restrict__ g,
                       const float* __restrict__ bb, float* __restrict__ h) {
  int b = blockIdx.x;
  int tid = threadIdx.x;   // 64
  __shared__ float v[LATENT_];
  __shared__ float mu_s, sc_s;
  if (tid < LATENT_) v[tid] = hp[b * LATENT_ + tid];
  __syncthreads();
  if (tid == 0) {
    float s = 0.f, sq = 0.f;
    for (int i = 0; i < LATENT_; i++) { s += v[i]; sq += v[i] * v[i]; }
    float mu = s * (1.f / LATENT_);
    float var = fmaxf(sq * (1.f / LATENT_) - mu * mu, 0.f);
    mu_s = mu; sc_s = rsqrtf(var + 1e-5f);
  }
  __syncthreads();
  if (tid < LATENT_) h[b * LATENT_ + tid] = eluf((v[tid] - mu_s) * sc_s * g[tid] + bb[tid]);
}

__global__ void lin2_sig(const float* __restrict__ h, const float* __restrict__ w,
                         const float* __restrict__ bias, float* __restrict__ out) {
  int gid = blockIdx.x * blockDim.x + threadIdx.x;
  if (gid >= B_ * NCELLS_) return;
  int b = gid / NCELLS_, c = gid % NCELLS_;
  const float* hr = h + b * LATENT_;
  const float* wr = w + (size_t)c * LATENT_;
  float s = bias[c];
  for (int j = 0; j < LATENT_; j++) s = fmaf(hr[j], wr[j], s);
  out[gid] = 1.f / (1.f + expf(-s));
}

extern "C" void kernel_launch(void* const* d_in, const int* in_sizes, int n_in,
                              void* d_out, int out_size, void* d_ws, size_t ws_size,
                              hipStream_t stream) {
  const int*   ids  = (const int*)  d_in[0];
  const float* we   = (const float*)d_in[1];
  const float* pe   = (const float*)d_in[2];
  const float* te   = (const float*)d_in[3];
  const float* elng = (const float*)d_in[4];
  const float* elnb = (const float*)d_in[5];
  const float* Wq   = (const float*)d_in[6];
  const float* bq   = (const float*)d_in[7];
  const float* Wk   = (const float*)d_in[8];
  const float* bk   = (const float*)d_in[9];
  const float* Wv   = (const float*)d_in[10];
  const float* bv   = (const float*)d_in[11];
  const float* Wo   = (const float*)d_in[12];
  const float* bo   = (const float*)d_in[13];
  const float* Wc1  = (const float*)d_in[14];
  const float* bc1  = (const float*)d_in[15];
  const float* Wc2  = (const float*)d_in[16];
  const float* bc2  = (const float*)d_in[17];
  const float* ng   = (const float*)d_in[18];
  const float* nb   = (const float*)d_in[19];
  const float* cw   = (const float*)d_in[20];
  const float* cb   = (const float*)d_in[21];
  const float* bng  = (const float*)d_in[22];
  const float* bnb  = (const float*)d_in[23];
  const float* bnm  = (const float*)d_in[24];
  const float* bnv  = (const float*)d_in[25];
  const float* l1w  = (const float*)d_in[26];
  const float* l1b  = (const float*)d_in[27];
  const float* l2g  = (const float*)d_in[28];
  const float* l2b  = (const float*)d_in[29];
  const float* l2w  = (const float*)d_in[30];
  const float* l2bi = (const float*)d_in[31];
  float* out = (float*)d_out;

  float* X  = (float*)d_ws;
  float* Q  = X + ND_;
  float* Kb = Q + ND_;
  float* V  = Kb + ND_;
  float* S  = V + ND_;
  float* Y  = S + ND_;
  float* G  = Q;             // [NROWS, DFF] overlays Q,K,V,S (4*ND == NROWS*DFF)
  float* CV = Q;             // conv out [B,384,510] overlays Q after layers
  float* F  = Kb;            // pooled features [B, 384*255] overlays K
  float* MV = Y + ND_;                          // [B,L]
  float* WT = MV + B_ * L_;                     // [B,6]
  int*   DT = (int*)(WT + B_ * TOPK_);          // [B,6]
  float* HP = (float*)(DT + B_ * TOPK_);        // [B,32]
  float* HH = HP + B_ * LATENT_;                // [B,32]

  // Embeddings + LN(eps=1e-12)
  embed_gather<<<2048, 256, 0, stream>>>(ids, we, pe, te, X);
  ln_rows<<<NROWS_, 256, 0, stream>>>(X, X, elng, elnb, 1e-12f);

  for (int l = 0; l < NL_; l++) {
    const float* wq = Wq + (size_t)l * D_ * D_;
    const float* wk = Wk + (size_t)l * D_ * D_;
    const float* wv = Wv + (size_t)l * D_ * D_;
    const float* wo = Wo + (size_t)l * D_ * D_;
    const float* w1 = Wc1 + (size_t)l * DFF_ * D_;
    const float* w2 = Wc2 + (size_t)l * D_ * DFF_;

    gemm_nt<0><<<dim3(D_ / BN, NROWS_ / BM), 256, 0, stream>>>(X, wq, bq + l * D_, Q, NROWS_, D_, D_);
    gemm_nt<0><<<dim3(D_ / BN, NROWS_ / BM), 256, 0, stream>>>(X, wk, bk + l * D_, Kb, NROWS_, D_, D_);
    gemm_nt<0><<<dim3(D_ / BN, NROWS_ / BM), 256, 0, stream>>>(X, wv, bv + l * D_, V, NROWS_, D_, D_);
    autocorr_mean<<<B_ * (L_ / 8), 256, 0, stream>>>(Q, Kb, MV);
    topk_softmax<<<B_, 256, 0, stream>>>(MV, WT, DT);
    agg_v<<<NROWS_, 256, 0, stream>>>(V, WT, DT, Q);
    gemm_nt<0><<<dim3(D_ / BN, NROWS_ / BM), 256, 0, stream>>>(Q, wo, bo + l * D_, Y, NROWS_, D_, D_);
    add_vec<<<2048, 256, 0, stream>>>(X, Y, S, ND_);
    decomp_k<<<(B_ * 4 * D_) / 256, 256, 0, stream>>>(S, X);
    gemm_nt<1><<<dim3(DFF_ / BN, NROWS_ / BM), 256, 0, stream>>>(X, w1, bc1 + l * DFF_, G, NROWS_, DFF_, D_);
    gemm_nt<0><<<dim3(D_ / BN, NROWS_ / BM), 256, 0, stream>>>(G, w2, bc2 + l * D_, Y, NROWS_, D_, DFF_);
    add_vec<<<2048, 256, 0, stream>>>(X, Y, S, ND_);
    decomp_k<<<(B_ * 4 * D_) / 256, 256, 0, stream>>>(S, X);
  }

  // my_Layernorm: LN(eps=1e-5) then subtract per-(b,d) mean over t
  ln_rows<<<NROWS_, 256, 0, stream>>>(X, S, ng, nb, 1e-5f);
  colmean_sub<<<(B_ * D_ + 255) / 256, 256, 0, stream>>>(S);

  // Head: conv1d -> BN -> ELU -> maxpool2 -> lin1 -> LN -> ELU -> lin2 -> sigmoid
  conv1d_k<<<dim3(CLEN_ / TCH, B_), 384, 0, stream>>>(S, cw, cb, CV);
  bn_elu_pool<<<(B_ * CMID_ * PLEN_ + 255) / 256, 256, 0, stream>>>(CV, bnm, bnv, bng, bnb, F);
  lin1_k<<<dim3(LATENT_, B_), 256, 0, stream>>>(F, l1w, l1b, HP);
  ln_elu<<<B_, 64, 0, stream>>>(HP, l2g, l2b, HH);
  lin2_sig<<<(B_ * NCELLS_ + 255) / 256, 256, 0, stream>>>(HH, l2w, l2bi, out);
}

// Round 2
// 2557.308 us; speedup vs baseline: 3.6311x; 3.6311x over previous
//
#include <hip/hip_runtime.h>
#include <hip/hip_bf16.h>

#define B_ 32
#define L_ 512
#define D_ 768
#define DFF_ 3072
#define NL_ 2
#define TOPK_ 6
#define CMID_ 384
#define CLEN_ 510
#define PLEN_ 255
#define LATENT_ 32
#define NCELLS_ 2034
#define NROWS_ (B_*L_)
#define ND_ ((size_t)B_*L_*D_)

typedef __attribute__((ext_vector_type(8))) short short8;
typedef __attribute__((ext_vector_type(4))) float f32x4;

static __device__ __forceinline__ float geluf(float x) {
  return 0.5f * x * (1.f + erff(x * 0.70710678118654752440f));
}
static __device__ __forceinline__ float eluf(float x) {
  return x > 0.f ? x : expm1f(x);
}
static __device__ __forceinline__ short bf16rn(float f) {
  unsigned u = __builtin_bit_cast(unsigned, f);
  u = u + 0x7FFFu + ((u >> 16) & 1u);
  return (short)(u >> 16);
}
static __device__ __forceinline__ float bf16tof(short s) {
  unsigned u = ((unsigned)(unsigned short)s) << 16;
  return __builtin_bit_cast(float, u);
}

// ---------------- embeddings ----------------
__global__ void embed_gather(const int* __restrict__ ids, const float* __restrict__ we,
                             const float* __restrict__ pe, const float* __restrict__ te,
                             float* __restrict__ x) {
  size_t stride = (size_t)gridDim.x * blockDim.x;
  for (size_t i = (size_t)blockIdx.x * blockDim.x + threadIdx.x; i < ND_; i += stride) {
    int d = (int)(i % D_);
    int row = (int)(i / D_);
    int t = row & (L_ - 1);
    int id = ids[row];
    x[i] = we[(size_t)id * D_ + d] + pe[(size_t)t * D_ + d] + te[d];
  }
}

// LayerNorm over last dim (768). One block per row.
__global__ __launch_bounds__(256) void ln_rows(const float* __restrict__ in, float* __restrict__ out,
                                               const float* __restrict__ g, const float* __restrict__ bta,
                                               float eps) {
  int row = blockIdx.x;
  int tid = threadIdx.x;
  const float* r = in + (size_t)row * D_;
  float v0 = r[tid], v1 = r[tid + 256], v2 = r[tid + 512];
  float s = v0 + v1 + v2;
  float sq = v0 * v0 + v1 * v1 + v2 * v2;
  __shared__ float rs[256], rq[256];
  rs[tid] = s; rq[tid] = sq;
  __syncthreads();
  for (int st = 128; st > 0; st >>= 1) {
    if (tid < st) { rs[tid] += rs[tid + st]; rq[tid] += rq[tid + st]; }
    __syncthreads();
  }
  __shared__ float smu, ssc;
  if (tid == 0) {
    float mu = rs[0] * (1.f / D_);
    float var = fmaxf(rq[0] * (1.f / D_) - mu * mu, 0.f);
    smu = mu; ssc = rsqrtf(var + eps);
  }
  __syncthreads();
  float mu = smu, sc = ssc;
  float* o = out + (size_t)row * D_;
  o[tid]       = (v0 - mu) * sc * g[tid]       + bta[tid];
  o[tid + 256] = (v1 - mu) * sc * g[tid + 256] + bta[tid + 256];
  o[tid + 512] = (v2 - mu) * sc * g[tid + 512] + bta[tid + 512];
}

// ---------------- MFMA GEMM (NT): C[m,o] = act(sum_k A[m,k]*W[o,k] + bias[o]) -------------
// A row stride = lda (>= K contiguous read of K elems per tile allowed); W row stride = K.
// bf16 via RNE; SPLIT adds hi/lo 3-MFMA compensation (~fp19 accuracy).
#define GBM 128
#define GBN 128
#define GBK 64

static __device__ __forceinline__ f32x4 mfma16(short8 a, short8 b, f32x4 c) {
  return __builtin_amdgcn_mfma_f32_16x16x32_bf16(a, b, c, 0, 0, 0);
}

template<int ACT, bool SPLIT>
__global__ __launch_bounds__(256) void gemm_mfma(const float* __restrict__ A, const float* __restrict__ W,
                                                 const float* __restrict__ bias, float* __restrict__ C,
                                                 int M, int O, int K, int lda,
                                                 long long sA, long long sW, long long sC) {
  constexpr int NP = SPLIT ? 2 : 1;
  __shared__ __align__(16) short As[NP][GBM * GBK];
  __shared__ __align__(16) short Ws[NP][GBN * GBK];
  const float* Ab = A + (size_t)blockIdx.z * sA;
  const float* Wb = W + (size_t)blockIdx.z * sW;
  float* Cb = C + (size_t)blockIdx.z * sC;
  int m0 = blockIdx.y * GBM, o0 = blockIdx.x * GBN;
  int tid = threadIdx.x;
  int wave = tid >> 6, lane = tid & 63;
  int wm = (wave >> 1) * 64, wn = (wave & 1) * 64;
  int lrow = lane & 15, lk = lane >> 4;

  f32x4 acc[4][4] = {};

  for (int k0 = 0; k0 < K; k0 += GBK) {
    // ---- stage: fp32 global -> bf16 (hi[/lo]) LDS with XOR swizzle ----
#pragma unroll
    for (int i = 0; i < 4; i++) {
      int u = tid + i * 256;           // 0..1023
      int row = u >> 3, koff = u & 7;
      int so = row * 64 + ((koff ^ (row & 7)) << 3);
      {
        const float* p = Ab + (size_t)(m0 + row) * lda + k0 + koff * 8;
        float4 a0 = *(const float4*)p, a1 = *(const float4*)(p + 4);
        float vv[8] = {a0.x, a0.y, a0.z, a0.w, a1.x, a1.y, a1.z, a1.w};
        short8 hi, lo;
#pragma unroll
        for (int j = 0; j < 8; j++) {
          short h = bf16rn(vv[j]);
          hi[j] = h;
          if (SPLIT) lo[j] = bf16rn(vv[j] - bf16tof(h));
        }
        *(short8*)&As[0][so] = hi;
        if (SPLIT) *(short8*)&As[1][so] = lo;
      }
      {
        const float* p = Wb + (size_t)(o0 + row) * K + k0 + koff * 8;
        float4 a0 = *(const float4*)p, a1 = *(const float4*)(p + 4);
        float vv[8] = {a0.x, a0.y, a0.z, a0.w, a1.x, a1.y, a1.z, a1.w};
        short8 hi, lo;
#pragma unroll
        for (int j = 0; j < 8; j++) {
          short h = bf16rn(vv[j]);
          hi[j] = h;
          if (SPLIT) lo[j] = bf16rn(vv[j] - bf16tof(h));
        }
        *(short8*)&Ws[0][so] = hi;
        if (SPLIT) *(short8*)&Ws[1][so] = lo;
      }
    }
    __syncthreads();
    // ---- compute: 2 k-steps of 16x16x32 ----
#pragma unroll
    for (int kk = 0; kk < 2; kk++) {
      short8 af[4], bf[4], afl[4], bfl[4];
      int koff = kk * 4 + lk;
#pragma unroll
      for (int i = 0; i < 4; i++) {
        int r = wm + i * 16 + lrow;
        int so = r * 64 + ((koff ^ (r & 7)) << 3);
        af[i] = *(const short8*)&As[0][so];
        if (SPLIT) afl[i] = *(const short8*)&As[1][so];
      }
#pragma unroll
      for (int j = 0; j < 4; j++) {
        int r = wn + j * 16 + lrow;
        int so = r * 64 + ((koff ^ (r & 7)) << 3);
        bf[j] = *(const short8*)&Ws[0][so];
        if (SPLIT) bfl[j] = *(const short8*)&Ws[1][so];
      }
#pragma unroll
      for (int i = 0; i < 4; i++)
#pragma unroll
        for (int j = 0; j < 4; j++) {
          if (SPLIT) {
            acc[i][j] = mfma16(afl[i], bf[j], acc[i][j]);
            acc[i][j] = mfma16(af[i], bfl[j], acc[i][j]);
          }
          acc[i][j] = mfma16(af[i], bf[j], acc[i][j]);
        }
    }
    __syncthreads();
  }
  // ---- epilogue: C/D layout col=lane&15, row=(lane>>4)*4+reg ----
#pragma unroll
  for (int i = 0; i < 4; i++) {
#pragma unroll
    for (int j = 0; j < 4; j++) {
      int col = o0 + wn + j * 16 + lrow;
      float bv = bias ? bias[col] : 0.f;
      int rowb = m0 + wm + i * 16 + lk * 4;
#pragma unroll
      for (int r = 0; r < 4; r++) {
        float v = acc[i][j][r] + bv;
        if (ACT == 1) v = geluf(v);
        Cb[(size_t)(rowb + r) * O + col] = v;
      }
    }
  }
}

// ---- circular-diagonal partial sums: mvp[b,rg,tau] = (1/D) sum_{r in rg} S[r, (r-tau)&511]
__global__ __launch_bounds__(256) void diag_partial(const float* __restrict__ S, float* __restrict__ mvp) {
  int b = blockIdx.x >> 3, rg = blockIdx.x & 7;
  int tid = threadIdx.x;
  const float* Sb = S + (size_t)b * L_ * L_;
  float a0 = 0.f, a1 = 0.f;
  int t0 = tid, t1 = tid + 256;
  int r0 = rg * 64;
  for (int r = r0; r < r0 + 64; r++) {
    a0 += Sb[(size_t)r * L_ + ((r - t0) & (L_ - 1))];
    a1 += Sb[(size_t)r * L_ + ((r - t1) & (L_ - 1))];
  }
  mvp[(size_t)blockIdx.x * L_ + t0] = a0 * (1.f / D_);
  mvp[(size_t)blockIdx.x * L_ + t1] = a1 * (1.f / D_);
}

// ---------------- top-k(6) + softmax over delays (sums 8 partials first) ----------------
__global__ __launch_bounds__(256) void topk_softmax(const float* __restrict__ mvp,
                                                    float* __restrict__ wout, int* __restrict__ dout) {
  int b = blockIdx.x, tid = threadIdx.x;
  __shared__ float vals[L_];
  __shared__ float rv[256];
  __shared__ int ri[256];
  __shared__ float wsel[TOPK_];
  __shared__ int dsel[TOPK_];
  float s0 = 0.f, s1 = 0.f;
  for (int rg = 0; rg < 8; rg++) {
    const float* p = mvp + (size_t)(b * 8 + rg) * L_;
    s0 += p[tid]; s1 += p[tid + 256];
  }
  vals[tid] = s0; vals[tid + 256] = s1;
  for (int kk = 0; kk < TOPK_; kk++) {
    __syncthreads();
    float v0 = vals[tid], v1 = vals[tid + 256];
    float bvv = v0; int bi = tid;
    if (v1 > v0) { bvv = v1; bi = tid + 256; }
    rv[tid] = bvv; ri[tid] = bi;
    __syncthreads();
    for (int st = 128; st > 0; st >>= 1) {
      if (tid < st) {
        float ov = rv[tid + st]; int oi = ri[tid + st];
        if (ov > rv[tid] || (ov == rv[tid] && oi < ri[tid])) { rv[tid] = ov; ri[tid] = oi; }
      }
      __syncthreads();
    }
    if (tid == 0) { wsel[kk] = rv[0]; dsel[kk] = ri[0]; vals[ri[0]] = -INFINITY; }
  }
  __syncthreads();
  if (tid == 0) {
    float mx = wsel[0];
    for (int i = 1; i < TOPK_; i++) mx = fmaxf(mx, wsel[i]);
    float e[TOPK_]; float sum = 0.f;
    for (int i = 0; i < TOPK_; i++) { e[i] = expf(wsel[i] - mx); sum += e[i]; }
    for (int i = 0; i < TOPK_; i++) { wout[b * TOPK_ + i] = e[i] / sum; dout[b * TOPK_ + i] = dsel[i]; }
  }
}

// out[b,t,d] = sum_k w[b,k] * v[b,(t+delay[b,k])%L,d]
__global__ __launch_bounds__(256) void agg_v(const float* __restrict__ v, const float* __restrict__ w,
                                             const int* __restrict__ dly, float* __restrict__ out) {
  int blr = blockIdx.x;      // b*L + t
  int b = blr >> 9, t = blr & 511;
  int tid = threadIdx.x;
  __shared__ float ww[TOPK_];
  __shared__ int rr[TOPK_];
  if (tid < TOPK_) { ww[tid] = w[b * TOPK_ + tid]; rr[tid] = (t + dly[b * TOPK_ + tid]) & (L_ - 1); }
  __syncthreads();
  const float* vb = v + (size_t)b * L_ * D_;
#pragma unroll
  for (int dd = 0; dd < 3; dd++) {
    int d = tid + dd * 256;
    float s = 0.f;
#pragma unroll
    for (int kk = 0; kk < TOPK_; kk++) s = fmaf(ww[kk], vb[(size_t)rr[kk] * D_ + d], s);
    out[(size_t)blr * D_ + d] = s;
  }
}

__global__ void add_vec(const float* __restrict__ a, const float* __restrict__ b,
                        float* __restrict__ o, size_t n) {
  size_t stride = (size_t)gridDim.x * blockDim.x;
  for (size_t i = (size_t)blockIdx.x * blockDim.x + threadIdx.x; i < n; i += stride)
    o[i] = a[i] + b[i];
}

// out = s - movavg25(s) with replicate padding
__global__ void decomp_k(const float* __restrict__ s, float* __restrict__ out) {
  int gid = blockIdx.x * blockDim.x + threadIdx.x;   // B*4*D
  if (gid >= B_ * 4 * D_) return;
  int d = gid % D_;
  int chunk = (gid / D_) & 3;
  int b = gid / (D_ * 4);
  const float* col = s + (size_t)b * L_ * D_ + d;
  float* ocol = out + (size_t)b * L_ * D_ + d;
  int t0 = chunk * 128;
  float wsum = 0.f;
  for (int u = t0 - 12; u <= t0 + 12; u++) {
    int uc = u < 0 ? 0 : (u > L_ - 1 ? L_ - 1 : u);
    wsum += col[(size_t)uc * D_];
  }
  for (int t = t0; t < t0 + 128; t++) {
    ocol[(size_t)t * D_] = col[(size_t)t * D_] - wsum * (1.f / 25.f);
    int ua = t + 13 > L_ - 1 ? L_ - 1 : t + 13;
    int ur = t - 12 < 0 ? 0 : t - 12;
    wsum += col[(size_t)ua * D_] - col[(size_t)ur * D_];
  }
}

// x[b,:,d] -= mean_t x[b,:,d]  (in place)
__global__ void colmean_sub(float* __restrict__ x) {
  int gid = blockIdx.x * blockDim.x + threadIdx.x;   // B*D
  if (gid >= B_ * D_) return;
  int d = gid % D_, b = gid / D_;
  float* col = x + (size_t)b * L_ * D_ + d;
  float s = 0.f;
  for (int t = 0; t < L_; t++) s += col[(size_t)t * D_];
  float mu = s * (1.f / L_);
  for (int t = 0; t < L_; t++) col[(size_t)t * D_] -= mu;
}

// conv weight repack: wt[o, j*768+i] = w[o, i, j]
__global__ void conv_w_repack(const float* __restrict__ w, float* __restrict__ wt) {
  int gid = blockIdx.x * blockDim.x + threadIdx.x;
  if (gid >= CMID_ * 3 * D_) return;
  int o = gid / (3 * D_);
  int k = gid % (3 * D_);
  int j = k / D_, i = k % D_;
  wt[gid] = w[((size_t)o * D_ + i) * 3 + j];
}

// BN+ELU+maxpool2 over conv-GEMM output laid out [b, t(512), o(384)]
__global__ void bn_elu_pool(const float* __restrict__ c, const float* __restrict__ bm,
                            const float* __restrict__ bvv, const float* __restrict__ bg,
                            const float* __restrict__ bb, float* __restrict__ f) {
  int gid = blockIdx.x * blockDim.x + threadIdx.x;
  if (gid >= B_ * CMID_ * PLEN_) return;
  int tp = gid % PLEN_;
  int o = (gid / PLEN_) % CMID_;
  int b = gid / (PLEN_ * CMID_);
  const float* base = c + ((size_t)b * 512 + 2 * tp) * CMID_ + o;
  float sc = rsqrtf(bvv[o] + 1e-5f) * bg[o];
  float sh = bb[o] - bm[o] * sc;
  float x0 = eluf(base[0] * sc + sh);
  float x1 = eluf(base[CMID_] * sc + sh);
  f[gid] = fmaxf(x0, x1);
}

__global__ __launch_bounds__(256) void lin1_k(const float* __restrict__ f, const float* __restrict__ w,
                                              const float* __restrict__ bias, float* __restrict__ out) {
  int o = blockIdx.x, b = blockIdx.y;
  int tid = threadIdx.x;
  const float4* fr = (const float4*)(f + (size_t)b * (CMID_ * PLEN_));
  const float4* wr = (const float4*)(w + (size_t)o * (CMID_ * PLEN_));
  const int n4 = CMID_ * PLEN_ / 4;
  float s = 0.f;
  for (int i = tid; i < n4; i += 256) {
    float4 a = fr[i], ww = wr[i];
    s += a.x * ww.x + a.y * ww.y + a.z * ww.z + a.w * ww.w;
  }
  __shared__ float red[256];
  red[tid] = s;
  __syncthreads();
  for (int st = 128; st > 0; st >>= 1) {
    if (tid < st) red[tid] += red[tid + st];
    __syncthreads();
  }
  if (tid == 0) out[b * LATENT_ + o] = red[0] + bias[o];
}

__global__ void ln_elu(const float* __restrict__ hp, const float* __restrict__ g,
                       const float* __restrict__ bb, float* __restrict__ h) {
  int b = blockIdx.x;
  int tid = threadIdx.x;   // 64
  __shared__ float v[LATENT_];
  __shared__ float mu_s, sc_s;
  if (tid < LATENT_) v[tid] = hp[b * LATENT_ + tid];
  __syncthreads();
  if (tid == 0) {
    float s = 0.f, sq = 0.f;
    for (int i = 0; i < LATENT_; i++) { s += v[i]; sq += v[i] * v[i]; }
    float mu = s * (1.f / LATENT_);
    float var = fmaxf(sq * (1.f / LATENT_) - mu * mu, 0.f);
    mu_s = mu; sc_s = rsqrtf(var + 1e-5f);
  }
  __syncthreads();
  if (tid < LATENT_) h[b * LATENT_ + tid] = eluf((v[tid] - mu_s) * sc_s * g[tid] + bb[tid]);
}

__global__ void lin2_sig(const float* __restrict__ h, const float* __restrict__ w,
                         const float* __restrict__ bias, float* __restrict__ out) {
  int gid = blockIdx.x * blockDim.x + threadIdx.x;
  if (gid >= B_ * NCELLS_) return;
  int b = gid / NCELLS_, c = gid % NCELLS_;
  const float* hr = h + b * LATENT_;
  const float* wr = w + (size_t)c * LATENT_;
  float s = bias[c];
  for (int j = 0; j < LATENT_; j++) s = fmaf(hr[j], wr[j], s);
  out[gid] = 1.f / (1.f + expf(-s));
}

extern "C" void kernel_launch(void* const* d_in, const int* in_sizes, int n_in,
                              void* d_out, int out_size, void* d_ws, size_t ws_size,
                              hipStream_t stream) {
  const int*   ids  = (const int*)  d_in[0];
  const float* we   = (const float*)d_in[1];
  const float* pe   = (const float*)d_in[2];
  const float* te   = (const float*)d_in[3];
  const float* elng = (const float*)d_in[4];
  const float* elnb = (const float*)d_in[5];
  const float* Wq   = (const float*)d_in[6];
  const float* bq   = (const float*)d_in[7];
  const float* Wk   = (const float*)d_in[8];
  const float* bk   = (const float*)d_in[9];
  const float* Wv   = (const float*)d_in[10];
  const float* bv   = (const float*)d_in[11];
  const float* Wo   = (const float*)d_in[12];
  const float* bo   = (const float*)d_in[13];
  const float* Wc1  = (const float*)d_in[14];
  const float* bc1  = (const float*)d_in[15];
  const float* Wc2  = (const float*)d_in[16];
  const float* bc2  = (const float*)d_in[17];
  const float* ng   = (const float*)d_in[18];
  const float* nb   = (const float*)d_in[19];
  const float* cw   = (const float*)d_in[20];
  const float* cb   = (const float*)d_in[21];
  const float* bng  = (const float*)d_in[22];
  const float* bnb  = (const float*)d_in[23];
  const float* bnm  = (const float*)d_in[24];
  const float* bnv  = (const float*)d_in[25];
  const float* l1w  = (const float*)d_in[26];
  const float* l1b  = (const float*)d_in[27];
  const float* l2g  = (const float*)d_in[28];
  const float* l2b  = (const float*)d_in[29];
  const float* l2w  = (const float*)d_in[30];
  const float* l2bi = (const float*)d_in[31];
  float* out = (float*)d_out;

  float* X  = (float*)d_ws;
  float* Q  = X + ND_;
  float* Kb = Q + ND_;
  float* V  = Kb + ND_;
  float* S  = V + ND_;
  float* Y  = S + ND_;
  float* G  = Q;             // [NROWS, DFF] overlays Q,K,V,S
  float* F  = Kb;            // pooled features [B, 384*255] overlays K (post-layers)
  float* MV = Y + ND_;                          // (unused slot kept for spacing)
  float* MVP = MV + B_ * L_;                    // [256, 512] partial diag sums
  float* WT = MVP + 256 * L_;                   // [B,6]
  int*   DT = (int*)(WT + B_ * TOPK_);          // [B,6]
  float* HP = (float*)(DT + B_ * TOPK_);        // [B,32]
  float* HH = HP + B_ * LATENT_;                // [B,32]
  float* WTC = HH + B_ * LATENT_;               // [384, 2304] repacked conv weights

  // conv weight repack (independent)
  conv_w_repack<<<(CMID_ * 3 * D_ + 255) / 256, 256, 0, stream>>>(cw, WTC);

  // Embeddings + LN(eps=1e-12)
  embed_gather<<<2048, 256, 0, stream>>>(ids, we, pe, te, X);
  ln_rows<<<NROWS_, 256, 0, stream>>>(X, X, elng, elnb, 1e-12f);

  for (int l = 0; l < NL_; l++) {
    const float* wq = Wq + (size_t)l * D_ * D_;
    const float* wk = Wk + (size_t)l * D_ * D_;
    const float* wv = Wv + (size_t)l * D_ * D_;
    const float* wo = Wo + (size_t)l * D_ * D_;
    const float* w1 = Wc1 + (size_t)l * DFF_ * D_;
    const float* w2 = Wc2 + (size_t)l * D_ * DFF_;

    // Q, K with split (protect top-k ordering); V single
    gemm_mfma<0, true><<<dim3(D_/GBN, NROWS_/GBM, 1), 256, 0, stream>>>(X, wq, bq + l*D_, Q, NROWS_, D_, D_, D_, 0, 0, 0);
    gemm_mfma<0, true><<<dim3(D_/GBN, NROWS_/GBM, 1), 256, 0, stream>>>(X, wk, bk + l*D_, Kb, NROWS_, D_, D_, D_, 0, 0, 0);
    gemm_mfma<0, false><<<dim3(D_/GBN, NROWS_/GBM, 1), 256, 0, stream>>>(X, wv, bv + l*D_, V, NROWS_, D_, D_, D_, 0, 0, 0);
    // scores S = Q K^T (batched, split) -> Y [B,512,512]
    gemm_mfma<0, true><<<dim3(L_/GBN, L_/GBM, B_), 256, 0, stream>>>(Q, Kb, nullptr, Y, L_, L_, D_, D_,
                                                                     (long long)L_*D_, (long long)L_*D_, (long long)L_*L_);
    diag_partial<<<256, 256, 0, stream>>>(Y, MVP);
    topk_softmax<<<B_, 256, 0, stream>>>(MVP, WT, DT);
    agg_v<<<NROWS_, 256, 0, stream>>>(V, WT, DT, Q);
    // O-projection
    gemm_mfma<0, false><<<dim3(D_/GBN, NROWS_/GBM, 1), 256, 0, stream>>>(Q, wo, bo + l*D_, Y, NROWS_, D_, D_, D_, 0, 0, 0);
    add_vec<<<2048, 256, 0, stream>>>(X, Y, S, ND_);
    decomp_k<<<(B_ * 4 * D_) / 256, 256, 0, stream>>>(S, X);
    // FFN
    gemm_mfma<1, false><<<dim3(DFF_/GBN, NROWS_/GBM, 1), 256, 0, stream>>>(X, w1, bc1 + l*DFF_, G, NROWS_, DFF_, D_, D_, 0, 0, 0);
    gemm_mfma<0, false><<<dim3(D_/GBN, NROWS_/GBM, 1), 256, 0, stream>>>(G, w2, bc2 + l*D_, Y, NROWS_, D_, DFF_, DFF_, 0, 0, 0);
    add_vec<<<2048, 256, 0, stream>>>(X, Y, S, ND_);
    decomp_k<<<(B_ * 4 * D_) / 256, 256, 0, stream>>>(S, X);
  }

  // my_Layernorm: LN(eps=1e-5) then subtract per-(b,d) mean over t
  ln_rows<<<NROWS_, 256, 0, stream>>>(X, S, ng, nb, 1e-5f);
  colmean_sub<<<(B_ * D_ + 255) / 256, 256, 0, stream>>>(S);

  // conv1d as GEMM: A rows = att[b, t..t+2, :] (lda=768, K=2304), W = WTC, C -> Y [b,t(512),o(384)]
  gemm_mfma<0, false><<<dim3(CMID_/GBN, NROWS_/GBM, 1), 256, 0, stream>>>(S, WTC, cb, Y, NROWS_, CMID_, 3*D_, D_, 0, 0, 0);
  bn_elu_pool<<<(B_ * CMID_ * PLEN_ + 255) / 256, 256, 0, stream>>>(Y, bnm, bnv, bng, bnb, F);
  lin1_k<<<dim3(LATENT_, B_), 256, 0, stream>>>(F, l1w, l1b, HP);
  ln_elu<<<B_, 64, 0, stream>>>(HP, l2g, l2b, HH);
  lin2_sig<<<(B_ * NCELLS_ + 255) / 256, 256, 0, stream>>>(HH, l2w, l2bi, out);
}

// Round 4
// 1651.134 us; speedup vs baseline: 5.6239x; 1.5488x over previous
//
#include <hip/hip_runtime.h>
#include <hip/hip_bf16.h>

#define B_ 32
#define L_ 512
#define D_ 768
#define DFF_ 3072
#define NL_ 2
#define TOPK_ 6
#define CMID_ 384
#define CLEN_ 510
#define PLEN_ 255
#define LATENT_ 32
#define NCELLS_ 2034
#define NROWS_ (B_*L_)
#define ND_ ((size_t)B_*L_*D_)

typedef unsigned short ushort_t;
typedef __attribute__((ext_vector_type(8))) short short8;
typedef __attribute__((ext_vector_type(4))) float f32x4;

typedef const __attribute__((address_space(1))) unsigned int* gp1;
typedef __attribute__((address_space(3))) unsigned int* lp3;

static __device__ __forceinline__ void gload16(const ushort_t* g, ushort_t* l) {
  __builtin_amdgcn_global_load_lds((gp1)g, (lp3)l, 16, 0, 0);
}

static __device__ __forceinline__ float geluf(float x) {
  return 0.5f * x * (1.f + erff(x * 0.70710678118654752440f));
}
static __device__ __forceinline__ float eluf(float x) {
  return x > 0.f ? x : expm1f(x);
}
static __device__ __forceinline__ ushort_t bf16rn(float f) {
  unsigned u = __builtin_bit_cast(unsigned, f);
  u = u + 0x7FFFu + ((u >> 16) & 1u);
  return (ushort_t)(u >> 16);
}
static __device__ __forceinline__ float bf16tof(ushort_t s) {
  unsigned u = ((unsigned)s) << 16;
  return __builtin_bit_cast(float, u);
}
static __device__ __forceinline__ f32x4 mfma16(short8 a, short8 b, f32x4 c) {
  return __builtin_amdgcn_mfma_f32_16x16x32_bf16(a, b, c, 0, 0, 0);
}

// ---------------- weight conversion ----------------
__global__ void wsplit(const float* __restrict__ w, ushort_t* __restrict__ hi,
                       ushort_t* __restrict__ lo, size_t n) {
  size_t stride = (size_t)gridDim.x * blockDim.x;
  for (size_t i = (size_t)blockIdx.x * blockDim.x + threadIdx.x; i < n; i += stride) {
    float v = w[i];
    ushort_t h = bf16rn(v);
    hi[i] = h;
    if (lo) lo[i] = bf16rn(v - bf16tof(h));
  }
}

// conv weight repack+convert: wt[o, j*768+i] = bf16(w[o, i, j])
__global__ void conv_w_repack(const float* __restrict__ w, ushort_t* __restrict__ wt) {
  int gid = blockIdx.x * blockDim.x + threadIdx.x;
  if (gid >= CMID_ * 3 * D_) return;
  int o = gid / (3 * D_);
  int k = gid % (3 * D_);
  int j = k / D_, i = k % D_;
  wt[gid] = bf16rn(w[((size_t)o * D_ + i) * 3 + j]);
}

// ---------------- fused embeddings + LN -> fp32 + bf16 hi/lo planes ----------------
__global__ __launch_bounds__(256) void embed_ln(const int* __restrict__ ids, const float* __restrict__ we,
                                                const float* __restrict__ pe, const float* __restrict__ te,
                                                const float* __restrict__ g, const float* __restrict__ bta,
                                                float* __restrict__ xf, ushort_t* __restrict__ xh,
                                                ushort_t* __restrict__ xl) {
  int row = blockIdx.x;
  int tid = threadIdx.x;
  int t = row & (L_ - 1);
  int id = ids[row];
  float v[3];
#pragma unroll
  for (int dd = 0; dd < 3; dd++) {
    int c = tid + dd * 256;
    v[dd] = we[(size_t)id * D_ + c] + pe[(size_t)t * D_ + c] + te[c];
  }
  float s = v[0] + v[1] + v[2];
  float sq = v[0]*v[0] + v[1]*v[1] + v[2]*v[2];
  __shared__ float rs[256], rq[256];
  rs[tid] = s; rq[tid] = sq;
  __syncthreads();
  for (int st = 128; st > 0; st >>= 1) {
    if (tid < st) { rs[tid] += rs[tid + st]; rq[tid] += rq[tid + st]; }
    __syncthreads();
  }
  __shared__ float smu, ssc;
  if (tid == 0) {
    float mu = rs[0] * (1.f / D_);
    float var = fmaxf(rq[0] * (1.f / D_) - mu * mu, 0.f);
    smu = mu; ssc = rsqrtf(var + 1e-12f);
  }
  __syncthreads();
  float mu = smu, sc = ssc;
#pragma unroll
  for (int dd = 0; dd < 3; dd++) {
    int c = tid + dd * 256;
    size_t o = (size_t)row * D_ + c;
    float ov = (v[dd] - mu) * sc * g[c] + bta[c];
    xf[o] = ov;
    ushort_t h = bf16rn(ov);
    xh[o] = h;
    xl[o] = bf16rn(ov - bf16tof(h));
  }
}

// ---------------- LayerNorm (head) ----------------
__global__ __launch_bounds__(256) void ln_rows(const float* __restrict__ in, float* __restrict__ out,
                                               const float* __restrict__ g, const float* __restrict__ bta,
                                               float eps) {
  int row = blockIdx.x;
  int tid = threadIdx.x;
  const float* r = in + (size_t)row * D_;
  float v0 = r[tid], v1 = r[tid + 256], v2 = r[tid + 512];
  float s = v0 + v1 + v2;
  float sq = v0*v0 + v1*v1 + v2*v2;
  __shared__ float rs[256], rq[256];
  rs[tid] = s; rq[tid] = sq;
  __syncthreads();
  for (int st = 128; st > 0; st >>= 1) {
    if (tid < st) { rs[tid] += rs[tid + st]; rq[tid] += rq[tid + st]; }
    __syncthreads();
  }
  __shared__ float smu, ssc;
  if (tid == 0) {
    float mu = rs[0] * (1.f / D_);
    float var = fmaxf(rq[0] * (1.f / D_) - mu * mu, 0.f);
    smu = mu; ssc = rsqrtf(var + eps);
  }
  __syncthreads();
  float mu = smu, sc = ssc;
  float* o = out + (size_t)row * D_;
  o[tid]       = (v0 - mu) * sc * g[tid]       + bta[tid];
  o[tid + 256] = (v1 - mu) * sc * g[tid + 256] + bta[tid + 256];
  o[tid + 512] = (v2 - mu) * sc * g[tid + 512] + bta[tid + 512];
}

// ---------------- MFMA GEMM, bf16-plane inputs, global_load_lds staging -------------
// C[m,o] = act(sum_k A[m,k]*W[o,k] + bias[o] + Res[m,o]); NT; 128x128x64 tile; 4 waves.
// SPLIT: A/W have hi+lo planes, 3-MFMA compensation.
// EPI: 0 = fp32 store, 1 = bf16 store, 2 = bf16 hi+lo store, 3 = circular-diag partials.
template<int ACT, bool SPLIT, int EPI>
__global__ __launch_bounds__(256) void gemm_bf16(
    const ushort_t* __restrict__ Ah, const ushort_t* __restrict__ Al,
    const ushort_t* __restrict__ Wh, const ushort_t* __restrict__ Wl,
    const float* __restrict__ bias, const float* __restrict__ Res,
    void* __restrict__ C0, void* __restrict__ C1,
    int O, int K, int lda,
    long long sA, long long sW, long long sC,
    int nbx, int nby) {
  constexpr int NP = SPLIT ? 2 : 1;
  __shared__ __align__(16) ushort_t AsH[NP][128 * 64];
  __shared__ __align__(16) ushort_t WsH[NP][128 * 64];
  __shared__ float dsum[EPI == 3 ? 512 : 1];

  // block decode: bijective XCD swizzle (m204) + GROUP_M=8 rasterization
  int nwg = gridDim.x;
  int wg = blockIdx.x;
  {
    int qq = nwg >> 3, rr = nwg & 7;
    int xcd = wg & 7, idx = wg >> 3;
    wg = (xcd < rr ? xcd * (qq + 1) : rr * (qq + 1) + (xcd - rr) * qq) + idx;
  }
  int per_b = nbx * nby;
  int bz = wg / per_b;
  int rem = wg - bz * per_b;
  int gsz = nbx * 8;
  int grp = rem / gsz;
  int ing = rem - grp * gsz;
  int by0 = grp * 8;
  int gmx = min(8, nby - by0);
  int by = by0 + (ing % gmx);
  int bx = ing / gmx;

  const ushort_t* Ahb = Ah + (size_t)bz * sA;
  const ushort_t* Alb = SPLIT ? (Al + (size_t)bz * sA) : nullptr;
  const ushort_t* Whb = Wh + (size_t)bz * sW;
  const ushort_t* Wlb = SPLIT ? (Wl + (size_t)bz * sW) : nullptr;

  int m0 = by * 128, o0 = bx * 128;
  int tid = threadIdx.x;
  int wave = tid >> 6, lane = tid & 63;
  int wm = (wave >> 1) * 64, wn = (wave & 1) * 64;
  int lcol = lane & 15, lk = lane >> 4;

  if (EPI == 3) {
    for (int s = tid; s < 512; s += 256) dsum[s] = 0.f;
  }

  f32x4 acc[4][4] = {};

  // staging geometry: per wave, 4 chunks of 1KB; lane l -> row = chunk*8 + (l>>3),
  // LDS slot (l&7); source global k-chunk pre-swizzled: (l&7) ^ (row&7).
  int r8 = lane >> 3;                       // row & 7 (invariant over chunk idx)
  int kc = (((lane & 7) ^ r8) << 3);        // source chunk element offset (0..56)

  for (int k0 = 0; k0 < K; k0 += 64) {
#pragma unroll
    for (int i = 0; i < 4; i++) {
      int ch = wave * 4 + i;
      int row = ch * 8 + r8;
      size_t ga = (size_t)(m0 + row) * lda + k0 + kc;
      size_t gw = (size_t)(o0 + row) * K + k0 + kc;
      gload16(Ahb + ga, &AsH[0][ch * 512]);
      gload16(Whb + gw, &WsH[0][ch * 512]);
      if (SPLIT) {
        gload16(Alb + ga, &AsH[1][ch * 512]);
        gload16(Wlb + gw, &WsH[1][ch * 512]);
      }
    }
    __syncthreads();
#pragma unroll
    for (int kk = 0; kk < 2; kk++) {
      int c = kk * 4 + lk;
      short8 ah[4], bh[4], al[4], bl[4];
#pragma unroll
      for (int i = 0; i < 4; i++) {
        int r = wm + i * 16 + lcol;
        int so = r * 64 + ((c ^ (r & 7)) << 3);
        ah[i] = *(const short8*)&AsH[0][so];
        if (SPLIT) al[i] = *(const short8*)&AsH[1][so];
      }
#pragma unroll
      for (int j = 0; j < 4; j++) {
        int r = wn + j * 16 + lcol;
        int so = r * 64 + ((c ^ (r & 7)) << 3);
        bh[j] = *(const short8*)&WsH[0][so];
        if (SPLIT) bl[j] = *(const short8*)&WsH[1][so];
      }
#pragma unroll
      for (int i = 0; i < 4; i++)
#pragma unroll
        for (int j = 0; j < 4; j++) {
          if (SPLIT) {
            acc[i][j] = mfma16(ah[i], bl[j], acc[i][j]);
            acc[i][j] = mfma16(al[i], bh[j], acc[i][j]);
          }
          acc[i][j] = mfma16(ah[i], bh[j], acc[i][j]);
        }
    }
    __syncthreads();
  }

  if (EPI == 3) {
    // circular-diagonal reduce: delay = (row - col) & 511, rows/cols batch-relative
#pragma unroll
    for (int i = 0; i < 4; i++)
#pragma unroll
      for (int j = 0; j < 4; j++) {
        int col = o0 + wn + j * 16 + lcol;
        int rowb = m0 + wm + i * 16 + lk * 4;
#pragma unroll
        for (int r = 0; r < 4; r++)
          atomicAdd(&dsum[(rowb + r - col) & (L_ - 1)], acc[i][j][r]);
      }
    __syncthreads();
    float* mvp = (float*)C0;
    int blk = by * nbx + bx;
    for (int s = tid; s < 512; s += 256)
      mvp[((size_t)bz * 16 + blk) * 512 + s] = dsum[s] * (1.f / D_);
  } else {
#pragma unroll
    for (int i = 0; i < 4; i++)
#pragma unroll
      for (int j = 0; j < 4; j++) {
        int col = o0 + wn + j * 16 + lcol;
        float bv = bias ? bias[col] : 0.f;
        int rowb = m0 + wm + i * 16 + lk * 4;
#pragma unroll
        for (int r = 0; r < 4; r++) {
          float v = acc[i][j][r] + bv;
          if (ACT == 1) v = geluf(v);
          size_t off = (size_t)bz * sC + (size_t)(rowb + r) * O + col;
          if (EPI == 0) {
            if (Res) v += Res[off];
            ((float*)C0)[off] = v;
          }
          if (EPI == 1) ((ushort_t*)C0)[off] = bf16rn(v);
          if (EPI == 2) {
            ushort_t h = bf16rn(v);
            ((ushort_t*)C0)[off] = h;
            ((ushort_t*)C1)[off] = bf16rn(v - bf16tof(h));
          }
        }
      }
  }
}

// ---------------- top-k(6) + softmax over delays (sums 16 partials) ----------------
__global__ __launch_bounds__(256) void topk_softmax(const float* __restrict__ mvp,
                                                    float* __restrict__ wout, int* __restrict__ dout) {
  int b = blockIdx.x, tid = threadIdx.x;
  __shared__ float vals[L_];
  __shared__ float rv[256];
  __shared__ int ri[256];
  __shared__ float wsel[TOPK_];
  __shared__ int dsel[TOPK_];
  float s0 = 0.f, s1 = 0.f;
  for (int p = 0; p < 16; p++) {
    const float* pp = mvp + ((size_t)b * 16 + p) * L_;
    s0 += pp[tid]; s1 += pp[tid + 256];
  }
  vals[tid] = s0; vals[tid + 256] = s1;
  for (int kk = 0; kk < TOPK_; kk++) {
    __syncthreads();
    float v0 = vals[tid], v1 = vals[tid + 256];
    float bvv = v0; int bi = tid;
    if (v1 > v0) { bvv = v1; bi = tid + 256; }
    rv[tid] = bvv; ri[tid] = bi;
    __syncthreads();
    for (int st = 128; st > 0; st >>= 1) {
      if (tid < st) {
        float ov = rv[tid + st]; int oi = ri[tid + st];
        if (ov > rv[tid] || (ov == rv[tid] && oi < ri[tid])) { rv[tid] = ov; ri[tid] = oi; }
      }
      __syncthreads();
    }
    if (tid == 0) { wsel[kk] = rv[0]; dsel[kk] = ri[0]; vals[ri[0]] = -INFINITY; }
  }
  __syncthreads();
  if (tid == 0) {
    float mx = wsel[0];
    for (int i = 1; i < TOPK_; i++) mx = fmaxf(mx, wsel[i]);
    float e[TOPK_]; float sum = 0.f;
    for (int i = 0; i < TOPK_; i++) { e[i] = expf(wsel[i] - mx); sum += e[i]; }
    for (int i = 0; i < TOPK_; i++) { wout[b * TOPK_ + i] = e[i] / sum; dout[b * TOPK_ + i] = dsel[i]; }
  }
}

// out_bf16[b,t,d] = sum_k w[b,k] * v[b,(t+delay[b,k])%L,d]
__global__ __launch_bounds__(256) void agg_v(const float* __restrict__ v, const float* __restrict__ w,
                                             const int* __restrict__ dly, ushort_t* __restrict__ out) {
  int blr = blockIdx.x;      // b*L + t
  int b = blr >> 9, t = blr & 511;
  int tid = threadIdx.x;
  __shared__ float ww[TOPK_];
  __shared__ int rr[TOPK_];
  if (tid < TOPK_) { ww[tid] = w[b * TOPK_ + tid]; rr[tid] = (t + dly[b * TOPK_ + tid]) & (L_ - 1); }
  __syncthreads();
  const float* vb = v + (size_t)b * L_ * D_;
#pragma unroll
  for (int dd = 0; dd < 3; dd++) {
    int d = tid + dd * 256;
    float s = 0.f;
#pragma unroll
    for (int kk = 0; kk < TOPK_; kk++) s = fmaf(ww[kk], vb[(size_t)rr[kk] * D_ + d], s);
    out[(size_t)blr * D_ + d] = bf16rn(s);
  }
}

// race-free decomp: reads fp32 sum S, writes fp32 X + bf16 hi/lo planes (distinct buffers)
__global__ void decomp_pl(const float* __restrict__ s, float* __restrict__ xo,
                          ushort_t* __restrict__ xh, ushort_t* __restrict__ xl) {
  int gid = blockIdx.x * blockDim.x + threadIdx.x;   // B*4*D
  if (gid >= B_ * 4 * D_) return;
  int d = gid % D_;
  int chunk = (gid / D_) & 3;
  int b = gid / (D_ * 4);
  size_t base = (size_t)b * L_ * D_ + d;
  int t0 = chunk * 128;
  float wsum = 0.f;
  for (int u = t0 - 12; u <= t0 + 12; u++) {
    int uc = u < 0 ? 0 : (u > L_ - 1 ? L_ - 1 : u);
    wsum += s[base + (size_t)uc * D_];
  }
  for (int t = t0; t < t0 + 128; t++) {
    size_t o = base + (size_t)t * D_;
    float v = s[o] - wsum * (1.f / 25.f);
    xo[o] = v;
    ushort_t h = bf16rn(v);
    xh[o] = h;
    xl[o] = bf16rn(v - bf16tof(h));
    int ua = t + 13 > L_ - 1 ? L_ - 1 : t + 13;
    int ur = t - 12 < 0 ? 0 : t - 12;
    wsum += s[base + (size_t)ua * D_] - s[base + (size_t)ur * D_];
  }
}

// x[b,:,d] -= mean_t; write bf16 plane only
__global__ void colmean_bf16(const float* __restrict__ x, ushort_t* __restrict__ sh) {
  int gid = blockIdx.x * blockDim.x + threadIdx.x;   // B*D
  if (gid >= B_ * D_) return;
  int d = gid % D_, b = gid / D_;
  const float* col = x + (size_t)b * L_ * D_ + d;
  ushort_t* oc = sh + (size_t)b * L_ * D_ + d;
  float s = 0.f;
  for (int t = 0; t < L_; t++) s += col[(size_t)t * D_];
  float mu = s * (1.f / L_);
  for (int t = 0; t < L_; t++) oc[(size_t)t * D_] = bf16rn(col[(size_t)t * D_] - mu);
}

// BN+ELU+maxpool2 over conv-GEMM output [b, t(512), o(384)]
__global__ void bn_elu_pool(const float* __restrict__ c, const float* __restrict__ bm,
                            const float* __restrict__ bvv, const float* __restrict__ bg,
                            const float* __restrict__ bb, float* __restrict__ f) {
  int gid = blockIdx.x * blockDim.x + threadIdx.x;
  if (gid >= B_ * CMID_ * PLEN_) return;
  int tp = gid % PLEN_;
  int o = (gid / PLEN_) % CMID_;
  int b = gid / (PLEN_ * CMID_);
  const float* base = c + ((size_t)b * 512 + 2 * tp) * CMID_ + o;
  float sc = rsqrtf(bvv[o] + 1e-5f) * bg[o];
  float sh = bb[o] - bm[o] * sc;
  float x0 = eluf(base[0] * sc + sh);
  float x1 = eluf(base[CMID_] * sc + sh);
  f[gid] = fmaxf(x0, x1);
}

__global__ __launch_bounds__(256) void lin1_k(const float* __restrict__ f, const float* __restrict__ w,
                                              const float* __restrict__ bias, float* __restrict__ out) {
  int o = blockIdx.x, b = blockIdx.y;
  int tid = threadIdx.x;
  const float4* fr = (const float4*)(f + (size_t)b * (CMID_ * PLEN_));
  const float4* wr = (const float4*)(w + (size_t)o * (CMID_ * PLEN_));
  const int n4 = CMID_ * PLEN_ / 4;
  float s = 0.f;
  for (int i = tid; i < n4; i += 256) {
    float4 a = fr[i], ww = wr[i];
    s += a.x * ww.x + a.y * ww.y + a.z * ww.z + a.w * ww.w;
  }
  __shared__ float red[256];
  red[tid] = s;
  __syncthreads();
  for (int st = 128; st > 0; st >>= 1) {
    if (tid < st) red[tid] += red[tid + st];
    __syncthreads();
  }
  if (tid == 0) out[b * LATENT_ + o] = red[0] + bias[o];
}

__global__ void ln_elu(const float* __restrict__ hp, const float* __restrict__ g,
                       const float* __restrict__ bb, float* __restrict__ h) {
  int b = blockIdx.x;
  int tid = threadIdx.x;   // 64
  __shared__ float v[LATENT_];
  __shared__ float mu_s, sc_s;
  if (tid < LATENT_) v[tid] = hp[b * LATENT_ + tid];
  __syncthreads();
  if (tid == 0) {
    float s = 0.f, sq = 0.f;
    for (int i = 0; i < LATENT_; i++) { s += v[i]; sq += v[i] * v[i]; }
    float mu = s * (1.f / LATENT_);
    float var = fmaxf(sq * (1.f / LATENT_) - mu * mu, 0.f);
    mu_s = mu; sc_s = rsqrtf(var + 1e-5f);
  }
  __syncthreads();
  if (tid < LATENT_) h[b * LATENT_ + tid] = eluf((v[tid] - mu_s) * sc_s * g[tid] + bb[tid]);
}

__global__ void lin2_sig(const float* __restrict__ h, const float* __restrict__ w,
                         const float* __restrict__ bias, float* __restrict__ out) {
  int gid = blockIdx.x * blockDim.x + threadIdx.x;
  if (gid >= B_ * NCELLS_) return;
  int b = gid / NCELLS_, c = gid % NCELLS_;
  const float* hr = h + b * LATENT_;
  const float* wr = w + (size_t)c * LATENT_;
  float s = bias[c];
  for (int j = 0; j < LATENT_; j++) s = fmaf(hr[j], wr[j], s);
  out[gid] = 1.f / (1.f + expf(-s));
}

extern "C" void kernel_launch(void* const* d_in, const int* in_sizes, int n_in,
                              void* d_out, int out_size, void* d_ws, size_t ws_size,
                              hipStream_t stream) {
  const int*   ids  = (const int*)  d_in[0];
  const float* we   = (const float*)d_in[1];
  const float* pe   = (const float*)d_in[2];
  const float* te   = (const float*)d_in[3];
  const float* elng = (const float*)d_in[4];
  const float* elnb = (const float*)d_in[5];
  const float* Wq   = (const float*)d_in[6];
  const float* bq   = (const float*)d_in[7];
  const float* Wk   = (const float*)d_in[8];
  const float* bk   = (const float*)d_in[9];
  const float* Wv   = (const float*)d_in[10];
  const float* bv   = (const float*)d_in[11];
  const float* Wo   = (const float*)d_in[12];
  const float* bo   = (const float*)d_in[13];
  const float* Wc1  = (const float*)d_in[14];
  const float* bc1  = (const float*)d_in[15];
  const float* Wc2  = (const float*)d_in[16];
  const float* bc2  = (const float*)d_in[17];
  const float* ng   = (const float*)d_in[18];
  const float* nb   = (const float*)d_in[19];
  const float* cw   = (const float*)d_in[20];
  const float* cb   = (const float*)d_in[21];
  const float* bng  = (const float*)d_in[22];
  const float* bnb  = (const float*)d_in[23];
  const float* bnm  = (const float*)d_in[24];
  const float* bnv  = (const float*)d_in[25];
  const float* l1w  = (const float*)d_in[26];
  const float* l1b  = (const float*)d_in[27];
  const float* l2g  = (const float*)d_in[28];
  const float* l2b  = (const float*)d_in[29];
  const float* l2w  = (const float*)d_in[30];
  const float* l2bi = (const float*)d_in[31];
  float* out = (float*)d_out;

  // ---- workspace carve-up ----
  char* wp = (char*)d_ws;
  auto alloc = [&](size_t bytes) { char* p = wp; wp += (bytes + 255) & ~(size_t)255; return p; };
  float*    Xf  = (float*)   alloc(ND_ * 4);
  ushort_t* Xh  = (ushort_t*)alloc(ND_ * 2);
  ushort_t* Xl  = (ushort_t*)alloc(ND_ * 2);
  ushort_t* R1  = (ushort_t*)alloc(ND_ * 2 * 4);   // Qh|Ql|Kh|Kl ; AGh=Qh ; Gh=whole ; F(head)
  float*    V   = (float*)   alloc(ND_ * 4);       // head: LN output
  float*    Y   = (float*)   alloc(ND_ * 4);       // GEMM fp32 outs (with residual); head: conv out
  float*    MVP = (float*)   alloc((size_t)B_ * 16 * L_ * 4);
  float*    WT  = (float*)   alloc(B_ * TOPK_ * 4);
  int*      DT  = (int*)     alloc(B_ * TOPK_ * 4);
  float*    HP  = (float*)   alloc(B_ * LATENT_ * 4);
  float*    HH  = (float*)   alloc(B_ * LATENT_ * 4);
  const size_t DD = (size_t)D_ * D_, DF = (size_t)DFF_ * D_;
  ushort_t* WqH = (ushort_t*)alloc(NL_ * DD * 2);
  ushort_t* WqL = (ushort_t*)alloc(NL_ * DD * 2);
  ushort_t* WkH = (ushort_t*)alloc(NL_ * DD * 2);
  ushort_t* WkL = (ushort_t*)alloc(NL_ * DD * 2);
  ushort_t* WvH = (ushort_t*)alloc(NL_ * DD * 2);
  ushort_t* WoH = (ushort_t*)alloc(NL_ * DD * 2);
  ushort_t* W1H = (ushort_t*)alloc(NL_ * DF * 2);
  ushort_t* W2H = (ushort_t*)alloc(NL_ * DF * 2);
  ushort_t* WTC = (ushort_t*)alloc((size_t)CMID_ * 3 * D_ * 2);

  ushort_t* Qh = R1;
  ushort_t* Ql = R1 + ND_;
  ushort_t* Kh = R1 + 2 * ND_;
  ushort_t* Kl = R1 + 3 * ND_;
  ushort_t* AGh = R1;          // overlays Qh (Q dead after scores)
  ushort_t* Gh = R1;           // FFN mid, overlays whole R1
  float*    F  = (float*)R1;   // head pooled features
  ushort_t* Sh = Xh;           // head bf16 plane (X planes dead at head)

  // ---- weight conversion (independent of activations) ----
  wsplit<<<512, 256, 0, stream>>>(Wq, WqH, WqL, NL_ * DD);
  wsplit<<<512, 256, 0, stream>>>(Wk, WkH, WkL, NL_ * DD);
  wsplit<<<512, 256, 0, stream>>>(Wv, WvH, nullptr, NL_ * DD);
  wsplit<<<512, 256, 0, stream>>>(Wo, WoH, nullptr, NL_ * DD);
  wsplit<<<1024, 256, 0, stream>>>(Wc1, W1H, nullptr, NL_ * DF);
  wsplit<<<1024, 256, 0, stream>>>(Wc2, W2H, nullptr, NL_ * DF);
  conv_w_repack<<<(CMID_ * 3 * D_ + 255) / 256, 256, 0, stream>>>(cw, WTC);

  // ---- embeddings + LN ----
  embed_ln<<<NROWS_, 256, 0, stream>>>(ids, we, pe, te, elng, elnb, Xf, Xh, Xl);

  for (int l = 0; l < NL_; l++) {
    // Q, K (split, bf16 hi+lo outputs); V (plain, fp32 out)
    gemm_bf16<0, true, 2><<<768, 256, 0, stream>>>(Xh, Xl, WqH + l*DD, WqL + l*DD, bq + l*D_, nullptr,
                                                   Qh, Ql, D_, D_, D_, 0, 0, 0, 6, 128);
    gemm_bf16<0, true, 2><<<768, 256, 0, stream>>>(Xh, Xl, WkH + l*DD, WkL + l*DD, bk + l*D_, nullptr,
                                                   Kh, Kl, D_, D_, D_, 0, 0, 0, 6, 128);
    gemm_bf16<0, false, 0><<<768, 256, 0, stream>>>(Xh, nullptr, WvH + l*DD, nullptr, bv + l*D_, nullptr,
                                                    V, nullptr, D_, D_, D_, 0, 0, 0, 6, 128);
    // scores -> circular-delay partials (batched, split)
    gemm_bf16<0, true, 3><<<512, 256, 0, stream>>>(Qh, Ql, Kh, Kl, nullptr, nullptr,
                                                   MVP, nullptr, L_, D_, D_,
                                                   (long long)L_ * D_, (long long)L_ * D_, 0, 4, 4);
    topk_softmax<<<B_, 256, 0, stream>>>(MVP, WT, DT);
    agg_v<<<NROWS_, 256, 0, stream>>>(V, WT, DT, AGh);
    // O-projection with fused residual: Y = X + attn_out
    gemm_bf16<0, false, 0><<<768, 256, 0, stream>>>(AGh, nullptr, WoH + l*DD, nullptr, bo + l*D_, Xf,
                                                    Y, nullptr, D_, D_, D_, 0, 0, 0, 6, 128);
    decomp_pl<<<(B_ * 4 * D_) / 256, 256, 0, stream>>>(Y, Xf, Xh, Xl);
    // FFN
    gemm_bf16<1, false, 1><<<3072, 256, 0, stream>>>(Xh, nullptr, W1H + l*DF, nullptr, bc1 + l*DFF_, nullptr,
                                                     Gh, nullptr, DFF_, D_, D_, 0, 0, 0, 24, 128);
    gemm_bf16<0, false, 0><<<768, 256, 0, stream>>>(Gh, nullptr, W2H + l*DF, nullptr, bc2 + l*D_, Xf,
                                                    Y, nullptr, D_, DFF_, DFF_, 0, 0, 0, 6, 128);
    decomp_pl<<<(B_ * 4 * D_) / 256, 256, 0, stream>>>(Y, Xf, Xh, Xl);
  }

  // my_Layernorm + column-center, bf16 plane for conv
  ln_rows<<<NROWS_, 256, 0, stream>>>(Xf, V, ng, nb, 1e-5f);
  colmean_bf16<<<(B_ * D_ + 255) / 256, 256, 0, stream>>>(V, Sh);

  // conv1d as GEMM (lda=768, K=2304, out [b,t,384] fp32 in Y)
  gemm_bf16<0, false, 0><<<384, 256, 0, stream>>>(Sh, nullptr, WTC, nullptr, cb, nullptr,
                                                  Y, nullptr, CMID_, 3 * D_, D_, 0, 0, 0, 3, 128);
  bn_elu_pool<<<(B_ * CMID_ * PLEN_ + 255) / 256, 256, 0, stream>>>(Y, bnm, bnv, bng, bnb, F);
  lin1_k<<<dim3(LATENT_, B_), 256, 0, stream>>>(F, l1w, l1b, HP);
  ln_elu<<<B_, 64, 0, stream>>>(HP, l2g, l2b, HH);
  lin2_sig<<<(B_ * NCELLS_ + 255) / 256, 256, 0, stream>>>(HH, l2w, l2bi, out);
}

// Round 5
// 1624.904 us; speedup vs baseline: 5.7147x; 1.0161x over previous
//
#include <hip/hip_runtime.h>
#include <hip/hip_bf16.h>

#define B_ 32
#define L_ 512
#define D_ 768
#define DFF_ 3072
#define NL_ 2
#define TOPK_ 6
#define CMID_ 384
#define CLEN_ 510
#define PLEN_ 255
#define LATENT_ 32
#define NCELLS_ 2034
#define NROWS_ (B_*L_)
#define ND_ ((size_t)B_*L_*D_)

typedef unsigned short ushort_t;
typedef __attribute__((ext_vector_type(8))) short short8;
typedef __attribute__((ext_vector_type(4))) float f32x4;

typedef const __attribute__((address_space(1))) unsigned int* gp1;
typedef __attribute__((address_space(3))) unsigned int* lp3;

static __device__ __forceinline__ void gload16(const ushort_t* g, ushort_t* l) {
  __builtin_amdgcn_global_load_lds((gp1)g, (lp3)l, 16, 0, 0);
}

static __device__ __forceinline__ float geluf(float x) {
  return 0.5f * x * (1.f + erff(x * 0.70710678118654752440f));
}
static __device__ __forceinline__ float eluf(float x) {
  return x > 0.f ? x : expm1f(x);
}
static __device__ __forceinline__ ushort_t bf16rn(float f) {
  unsigned u = __builtin_bit_cast(unsigned, f);
  u = u + 0x7FFFu + ((u >> 16) & 1u);
  return (ushort_t)(u >> 16);
}
static __device__ __forceinline__ float bf16tof(ushort_t s) {
  unsigned u = ((unsigned)s) << 16;
  return __builtin_bit_cast(float, u);
}
static __device__ __forceinline__ f32x4 mfma16(short8 a, short8 b, f32x4 c) {
  return __builtin_amdgcn_mfma_f32_16x16x32_bf16(a, b, c, 0, 0, 0);
}

// ---------------- weight conversion ----------------
__global__ void wsplit(const float* __restrict__ w, ushort_t* __restrict__ hi,
                       ushort_t* __restrict__ lo, size_t n) {
  size_t stride = (size_t)gridDim.x * blockDim.x;
  for (size_t i = (size_t)blockIdx.x * blockDim.x + threadIdx.x; i < n; i += stride) {
    float v = w[i];
    ushort_t h = bf16rn(v);
    hi[i] = h;
    if (lo) lo[i] = bf16rn(v - bf16tof(h));
  }
}

// transpose + split: hiT[a,j] (+loT) = split(in[j,a]); per-layer via blockIdx.z (stride D_*D_)
__global__ __launch_bounds__(256) void tsplit(const float* __restrict__ in, ushort_t* __restrict__ hiT,
                                              ushort_t* __restrict__ loT) {
  __shared__ float tile[32][33];
  size_t off = (size_t)blockIdx.z * D_ * D_;
  int bx = blockIdx.x * 32, by = blockIdx.y * 32;
  int tx = threadIdx.x & 31, ty = threadIdx.x >> 5;
#pragma unroll
  for (int i = 0; i < 32; i += 8)
    tile[ty + i][tx] = in[off + (size_t)(by + ty + i) * D_ + bx + tx];
  __syncthreads();
#pragma unroll
  for (int i = 0; i < 32; i += 8) {
    float v = tile[tx][ty + i];
    ushort_t h = bf16rn(v);
    size_t o = off + (size_t)(bx + ty + i) * D_ + by + tx;
    hiT[o] = h;
    loT[o] = bf16rn(v - bf16tof(h));
  }
}

// bvo[a] = bo[a] + sum_j Wo[a,j]*bv[j]
__global__ void bvo_k(const float* __restrict__ wo, const float* __restrict__ bv,
                      const float* __restrict__ bo, float* __restrict__ bvo) {
  int a = blockIdx.x * 256 + threadIdx.x;
  if (a >= D_) return;
  float s = bo[a];
  for (int j = 0; j < D_; j++) s = fmaf(wo[(size_t)a * D_ + j], bv[j], s);
  bvo[a] = s;
}

// conv weight repack+convert: wt[o, j*768+i] = bf16(w[o, i, j])
__global__ void conv_w_repack(const float* __restrict__ w, ushort_t* __restrict__ wt) {
  int gid = blockIdx.x * blockDim.x + threadIdx.x;
  if (gid >= CMID_ * 3 * D_) return;
  int o = gid / (3 * D_);
  int k = gid % (3 * D_);
  int j = k / D_, i = k % D_;
  wt[gid] = bf16rn(w[((size_t)o * D_ + i) * 3 + j]);
}

// ---------------- fused embeddings + LN -> fp32 + bf16 hi/lo planes ----------------
__global__ __launch_bounds__(256) void embed_ln(const int* __restrict__ ids, const float* __restrict__ we,
                                                const float* __restrict__ pe, const float* __restrict__ te,
                                                const float* __restrict__ g, const float* __restrict__ bta,
                                                float* __restrict__ xf, ushort_t* __restrict__ xh,
                                                ushort_t* __restrict__ xl) {
  int row = blockIdx.x;
  int tid = threadIdx.x;
  int t = row & (L_ - 1);
  int id = ids[row];
  float v[3];
#pragma unroll
  for (int dd = 0; dd < 3; dd++) {
    int c = tid + dd * 256;
    v[dd] = we[(size_t)id * D_ + c] + pe[(size_t)t * D_ + c] + te[c];
  }
  float s = v[0] + v[1] + v[2];
  float sq = v[0]*v[0] + v[1]*v[1] + v[2]*v[2];
  __shared__ float rs[256], rq[256];
  rs[tid] = s; rq[tid] = sq;
  __syncthreads();
  for (int st = 128; st > 0; st >>= 1) {
    if (tid < st) { rs[tid] += rs[tid + st]; rq[tid] += rq[tid + st]; }
    __syncthreads();
  }
  __shared__ float smu, ssc;
  if (tid == 0) {
    float mu = rs[0] * (1.f / D_);
    float var = fmaxf(rq[0] * (1.f / D_) - mu * mu, 0.f);
    smu = mu; ssc = rsqrtf(var + 1e-12f);
  }
  __syncthreads();
  float mu = smu, sc = ssc;
#pragma unroll
  for (int dd = 0; dd < 3; dd++) {
    int c = tid + dd * 256;
    size_t o = (size_t)row * D_ + c;
    float ov = (v[dd] - mu) * sc * g[c] + bta[c];
    xf[o] = ov;
    ushort_t h = bf16rn(ov);
    xh[o] = h;
    xl[o] = bf16rn(ov - bf16tof(h));
  }
}

// ---------------- LayerNorm (head) ----------------
__global__ __launch_bounds__(256) void ln_rows(const float* __restrict__ in, float* __restrict__ out,
                                               const float* __restrict__ g, const float* __restrict__ bta,
                                               float eps) {
  int row = blockIdx.x;
  int tid = threadIdx.x;
  const float* r = in + (size_t)row * D_;
  float v0 = r[tid], v1 = r[tid + 256], v2 = r[tid + 512];
  float s = v0 + v1 + v2;
  float sq = v0*v0 + v1*v1 + v2*v2;
  __shared__ float rs[256], rq[256];
  rs[tid] = s; rq[tid] = sq;
  __syncthreads();
  for (int st = 128; st > 0; st >>= 1) {
    if (tid < st) { rs[tid] += rs[tid + st]; rq[tid] += rq[tid + st]; }
    __syncthreads();
  }
  __shared__ float smu, ssc;
  if (tid == 0) {
    float mu = rs[0] * (1.f / D_);
    float var = fmaxf(rq[0] * (1.f / D_) - mu * mu, 0.f);
    smu = mu; ssc = rsqrtf(var + eps);
  }
  __syncthreads();
  float mu = smu, sc = ssc;
  float* o = out + (size_t)row * D_;
  o[tid]       = (v0 - mu) * sc * g[tid]       + bta[tid];
  o[tid + 256] = (v1 - mu) * sc * g[tid + 256] + bta[tid + 256];
  o[tid + 512] = (v2 - mu) * sc * g[tid + 512] + bta[tid + 512];
}

// ---------------- MFMA GEMM, bf16-plane inputs, global_load_lds staging -------------
// C[m,o] = act(sum_k A[m,k]*W[o,k] + bias[o] + Res[m,o]); NT; 128x128x64 tile; 4 waves.
// SPLIT: A/W have hi+lo planes, 3-MFMA compensation.
// EPI: 0 = fp32 store, 1 = bf16 store, 2 = bf16 hi+lo store, 3 = circular-diag partials.
template<int ACT, bool SPLIT, int EPI>
__global__ __launch_bounds__(256) void gemm_bf16(
    const ushort_t* __restrict__ Ah, const ushort_t* __restrict__ Al,
    const ushort_t* __restrict__ Wh, const ushort_t* __restrict__ Wl,
    const float* __restrict__ bias, const float* __restrict__ Res,
    void* __restrict__ C0, void* __restrict__ C1,
    int O, int K, int lda,
    long long sA, long long sW, long long sC,
    int nbx, int nby) {
  constexpr int NP = SPLIT ? 2 : 1;
  __shared__ __align__(16) ushort_t AsH[NP][128 * 64];
  __shared__ __align__(16) ushort_t WsH[NP][128 * 64];
  __shared__ float dsum[EPI == 3 ? 512 : 1];

  // block decode: bijective XCD swizzle (m204) + GROUP_M=8 rasterization
  int nwg = gridDim.x;
  int wg = blockIdx.x;
  {
    int qq = nwg >> 3, rr = nwg & 7;
    int xcd = wg & 7, idx = wg >> 3;
    wg = (xcd < rr ? xcd * (qq + 1) : rr * (qq + 1) + (xcd - rr) * qq) + idx;
  }
  int per_b = nbx * nby;
  int bz = wg / per_b;
  int rem = wg - bz * per_b;
  int gsz = nbx * 8;
  int grp = rem / gsz;
  int ing = rem - grp * gsz;
  int by0 = grp * 8;
  int gmx = min(8, nby - by0);
  int by = by0 + (ing % gmx);
  int bx = ing / gmx;

  const ushort_t* Ahb = Ah + (size_t)bz * sA;
  const ushort_t* Alb = SPLIT ? (Al + (size_t)bz * sA) : nullptr;
  const ushort_t* Whb = Wh + (size_t)bz * sW;
  const ushort_t* Wlb = SPLIT ? (Wl + (size_t)bz * sW) : nullptr;

  int m0 = by * 128, o0 = bx * 128;
  int tid = threadIdx.x;
  int wave = tid >> 6, lane = tid & 63;
  int wm = (wave >> 1) * 64, wn = (wave & 1) * 64;
  int lcol = lane & 15, lk = lane >> 4;

  if (EPI == 3) {
    for (int s = tid; s < 512; s += 256) dsum[s] = 0.f;
  }

  f32x4 acc[4][4] = {};

  // staging geometry: per wave, 4 chunks of 1KB; lane l -> row = chunk*8 + (l>>3),
  // LDS slot (l&7); source global k-chunk pre-swizzled: (l&7) ^ (row&7).
  int r8 = lane >> 3;
  int kc = (((lane & 7) ^ r8) << 3);

  for (int k0 = 0; k0 < K; k0 += 64) {
#pragma unroll
    for (int i = 0; i < 4; i++) {
      int ch = wave * 4 + i;
      int row = ch * 8 + r8;
      size_t ga = (size_t)(m0 + row) * lda + k0 + kc;
      size_t gw = (size_t)(o0 + row) * K + k0 + kc;
      gload16(Ahb + ga, &AsH[0][ch * 512]);
      gload16(Whb + gw, &WsH[0][ch * 512]);
      if (SPLIT) {
        gload16(Alb + ga, &AsH[1][ch * 512]);
        gload16(Wlb + gw, &WsH[1][ch * 512]);
      }
    }
    __syncthreads();
#pragma unroll
    for (int kk = 0; kk < 2; kk++) {
      int c = kk * 4 + lk;
      short8 ah[4], bh[4], al[4], bl[4];
#pragma unroll
      for (int i = 0; i < 4; i++) {
        int r = wm + i * 16 + lcol;
        int so = r * 64 + ((c ^ (r & 7)) << 3);
        ah[i] = *(const short8*)&AsH[0][so];
        if (SPLIT) al[i] = *(const short8*)&AsH[1][so];
      }
#pragma unroll
      for (int j = 0; j < 4; j++) {
        int r = wn + j * 16 + lcol;
        int so = r * 64 + ((c ^ (r & 7)) << 3);
        bh[j] = *(const short8*)&WsH[0][so];
        if (SPLIT) bl[j] = *(const short8*)&WsH[1][so];
      }
#pragma unroll
      for (int i = 0; i < 4; i++)
#pragma unroll
        for (int j = 0; j < 4; j++) {
          if (SPLIT) {
            acc[i][j] = mfma16(ah[i], bl[j], acc[i][j]);
            acc[i][j] = mfma16(al[i], bh[j], acc[i][j]);
          }
          acc[i][j] = mfma16(ah[i], bh[j], acc[i][j]);
        }
    }
    __syncthreads();
  }

  if (EPI == 3) {
#pragma unroll
    for (int i = 0; i < 4; i++)
#pragma unroll
      for (int j = 0; j < 4; j++) {
        int col = o0 + wn + j * 16 + lcol;
        int rowb = m0 + wm + i * 16 + lk * 4;
#pragma unroll
        for (int r = 0; r < 4; r++)
          atomicAdd(&dsum[(rowb + r - col) & (L_ - 1)], acc[i][j][r]);
      }
    __syncthreads();
    float* mvp = (float*)C0;
    int blk = by * nbx + bx;
    for (int s = tid; s < 512; s += 256)
      mvp[((size_t)bz * 16 + blk) * 512 + s] = dsum[s] * (1.f / D_);
  } else {
#pragma unroll
    for (int i = 0; i < 4; i++)
#pragma unroll
      for (int j = 0; j < 4; j++) {
        int col = o0 + wn + j * 16 + lcol;
        float bv = bias ? bias[col] : 0.f;
        int rowb = m0 + wm + i * 16 + lk * 4;
#pragma unroll
        for (int r = 0; r < 4; r++) {
          float v = acc[i][j][r] + bv;
          if (ACT == 1) v = geluf(v);
          size_t off = (size_t)bz * sC + (size_t)(rowb + r) * O + col;
          if (EPI == 0) {
            if (Res) v += Res[off];
            ((float*)C0)[off] = v;
          }
          if (EPI == 1) ((ushort_t*)C0)[off] = bf16rn(v);
          if (EPI == 2) {
            ushort_t h = bf16rn(v);
            ((ushort_t*)C0)[off] = h;
            ((ushort_t*)C1)[off] = bf16rn(v - bf16tof(h));
          }
        }
      }
  }
}

// ---------------- top-k(6) + softmax over delays (sums 16 partials) ----------------
__global__ __launch_bounds__(256) void topk_softmax(const float* __restrict__ mvp,
                                                    float* __restrict__ wout, int* __restrict__ dout) {
  int b = blockIdx.x, tid = threadIdx.x;
  __shared__ float vals[L_];
  __shared__ float rv[256];
  __shared__ int ri[256];
  __shared__ float wsel[TOPK_];
  __shared__ int dsel[TOPK_];
  float s0 = 0.f, s1 = 0.f;
  for (int p = 0; p < 16; p++) {
    const float* pp = mvp + ((size_t)b * 16 + p) * L_;
    s0 += pp[tid]; s1 += pp[tid + 256];
  }
  vals[tid] = s0; vals[tid + 256] = s1;
  for (int kk = 0; kk < TOPK_; kk++) {
    __syncthreads();
    float v0 = vals[tid], v1 = vals[tid + 256];
    float bvv = v0; int bi = tid;
    if (v1 > v0) { bvv = v1; bi = tid + 256; }
    rv[tid] = bvv; ri[tid] = bi;
    __syncthreads();
    for (int st = 128; st > 0; st >>= 1) {
      if (tid < st) {
        float ov = rv[tid + st]; int oi = ri[tid + st];
        if (ov > rv[tid] || (ov == rv[tid] && oi < ri[tid])) { rv[tid] = ov; ri[tid] = oi; }
      }
      __syncthreads();
    }
    if (tid == 0) { wsel[kk] = rv[0]; dsel[kk] = ri[0]; vals[ri[0]] = -INFINITY; }
  }
  __syncthreads();
  if (tid == 0) {
    float mx = wsel[0];
    for (int i = 1; i < TOPK_; i++) mx = fmaxf(mx, wsel[i]);
    float e[TOPK_]; float sum = 0.f;
    for (int i = 0; i < TOPK_; i++) { e[i] = expf(wsel[i] - mx); sum += e[i]; }
    for (int i = 0; i < TOPK_; i++) { wout[b * TOPK_ + i] = e[i] / sum; dout[b * TOPK_ + i] = dsel[i]; }
  }
}

// y[b,t,d] = sum_k w[b,k] * P[b,(t+delay[b,k])%L,d] + xf[b,t,d]   (fused residual)
__global__ __launch_bounds__(256) void agg_res(const float* __restrict__ P, const float* __restrict__ w,
                                               const int* __restrict__ dly, const float* __restrict__ xf,
                                               float* __restrict__ y) {
  int blr = blockIdx.x;      // b*L + t
  int b = blr >> 9, t = blr & 511;
  int tid = threadIdx.x;
  __shared__ float ww[TOPK_];
  __shared__ int rr[TOPK_];
  if (tid < TOPK_) { ww[tid] = w[b * TOPK_ + tid]; rr[tid] = (t + dly[b * TOPK_ + tid]) & (L_ - 1); }
  __syncthreads();
  const float* pb = P + (size_t)b * L_ * D_;
#pragma unroll
  for (int dd = 0; dd < 3; dd++) {
    int d = tid + dd * 256;
    float s = xf[(size_t)blr * D_ + d];
#pragma unroll
    for (int kk = 0; kk < TOPK_; kk++) s = fmaf(ww[kk], pb[(size_t)rr[kk] * D_ + d], s);
    y[(size_t)blr * D_ + d] = s;
  }
}

// race-free decomp: reads fp32 sum S, writes fp32 X (+ optional bf16 hi/lo planes)
__global__ void decomp_pl(const float* __restrict__ s, float* __restrict__ xo,
                          ushort_t* __restrict__ xh, ushort_t* __restrict__ xl) {
  int gid = blockIdx.x * blockDim.x + threadIdx.x;   // B*4*D
  if (gid >= B_ * 4 * D_) return;
  int d = gid % D_;
  int chunk = (gid / D_) & 3;
  int b = gid / (D_ * 4);
  size_t base = (size_t)b * L_ * D_ + d;
  int t0 = chunk * 128;
  float wsum = 0.f;
  for (int u = t0 - 12; u <= t0 + 12; u++) {
    int uc = u < 0 ? 0 : (u > L_ - 1 ? L_ - 1 : u);
    wsum += s[base + (size_t)uc * D_];
  }
  for (int t = t0; t < t0 + 128; t++) {
    size_t o = base + (size_t)t * D_;
    float v = s[o] - wsum * (1.f / 25.f);
    xo[o] = v;
    if (xh) {
      ushort_t h = bf16rn(v);
      xh[o] = h;
      xl[o] = bf16rn(v - bf16tof(h));
    }
    int ua = t + 13 > L_ - 1 ? L_ - 1 : t + 13;
    int ur = t - 12 < 0 ? 0 : t - 12;
    wsum += s[base + (size_t)ua * D_] - s[base + (size_t)ur * D_];
  }
}

// x[b,:,d] -= mean_t; write bf16 plane only
__global__ void colmean_bf16(const float* __restrict__ x, ushort_t* __restrict__ sh) {
  int gid = blockIdx.x * blockDim.x + threadIdx.x;   // B*D
  if (gid >= B_ * D_) return;
  int d = gid % D_, b = gid / D_;
  const float* col = x + (size_t)b * L_ * D_ + d;
  ushort_t* oc = sh + (size_t)b * L_ * D_ + d;
  float s = 0.f;
  for (int t = 0; t < L_; t++) s += col[(size_t)t * D_];
  float mu = s * (1.f / L_);
  for (int t = 0; t < L_; t++) oc[(size_t)t * D_] = bf16rn(col[(size_t)t * D_] - mu);
}

// BN+ELU+maxpool2 over conv-GEMM output [b, t(512), o(384)]
__global__ void bn_elu_pool(const float* __restrict__ c, const float* __restrict__ bm,
                            const float* __restrict__ bvv, const float* __restrict__ bg,
                            const float* __restrict__ bb, float* __restrict__ f) {
  int gid = blockIdx.x * blockDim.x + threadIdx.x;
  if (gid >= B_ * CMID_ * PLEN_) return;
  int tp = gid % PLEN_;
  int o = (gid / PLEN_) % CMID_;
  int b = gid / (PLEN_ * CMID_);
  const float* base = c + ((size_t)b * 512 + 2 * tp) * CMID_ + o;
  float sc = rsqrtf(bvv[o] + 1e-5f) * bg[o];
  float sh = bb[o] - bm[o] * sc;
  float x0 = eluf(base[0] * sc + sh);
  float x1 = eluf(base[CMID_] * sc + sh);
  f[gid] = fmaxf(x0, x1);
}

__global__ __launch_bounds__(256) void lin1_k(const float* __restrict__ f, const float* __restrict__ w,
                                              const float* __restrict__ bias, float* __restrict__ out) {
  int o = blockIdx.x, b = blockIdx.y;
  int tid = threadIdx.x;
  const float4* fr = (const float4*)(f + (size_t)b * (CMID_ * PLEN_));
  const float4* wr = (const float4*)(w + (size_t)o * (CMID_ * PLEN_));
  const int n4 = CMID_ * PLEN_ / 4;
  float s = 0.f;
  for (int i = tid; i < n4; i += 256) {
    float4 a = fr[i], ww = wr[i];
    s += a.x * ww.x + a.y * ww.y + a.z * ww.z + a.w * ww.w;
  }
  __shared__ float red[256];
  red[tid] = s;
  __syncthreads();
  for (int st = 128; st > 0; st >>= 1) {
    if (tid < st) red[tid] += red[tid + st];
    __syncthreads();
  }
  if (tid == 0) out[b * LATENT_ + o] = red[0] + bias[o];
}

__global__ void ln_elu(const float* __restrict__ hp, const float* __restrict__ g,
                       const float* __restrict__ bb, float* __restrict__ h) {
  int b = blockIdx.x;
  int tid = threadIdx.x;   // 64
  __shared__ float v[LATENT_];
  __shared__ float mu_s, sc_s;
  if (tid < LATENT_) v[tid] = hp[b * LATENT_ + tid];
  __syncthreads();
  if (tid == 0) {
    float s = 0.f, sq = 0.f;
    for (int i = 0; i < LATENT_; i++) { s += v[i]; sq += v[i] * v[i]; }
    float mu = s * (1.f / LATENT_);
    float var = fmaxf(sq * (1.f / LATENT_) - mu * mu, 0.f);
    mu_s = mu; sc_s = rsqrtf(var + 1e-5f);
  }
  __syncthreads();
  if (tid < LATENT_) h[b * LATENT_ + tid] = eluf((v[tid] - mu_s) * sc_s * g[tid] + bb[tid]);
}

__global__ void lin2_sig(const float* __restrict__ h, const float* __restrict__ w,
                         const float* __restrict__ bias, float* __restrict__ out) {
  int gid = blockIdx.x * blockDim.x + threadIdx.x;
  if (gid >= B_ * NCELLS_) return;
  int b = gid / NCELLS_, c = gid % NCELLS_;
  const float* hr = h + b * LATENT_;
  const float* wr = w + (size_t)c * LATENT_;
  float s = bias[c];
  for (int j = 0; j < LATENT_; j++) s = fmaf(hr[j], wr[j], s);
  out[gid] = 1.f / (1.f + expf(-s));
}

extern "C" void kernel_launch(void* const* d_in, const int* in_sizes, int n_in,
                              void* d_out, int out_size, void* d_ws, size_t ws_size,
                              hipStream_t stream) {
  const int*   ids  = (const int*)  d_in[0];
  const float* we   = (const float*)d_in[1];
  const float* pe   = (const float*)d_in[2];
  const float* te   = (const float*)d_in[3];
  const float* elng = (const float*)d_in[4];
  const float* elnb = (const float*)d_in[5];
  const float* Wq   = (const float*)d_in[6];
  const float* bq   = (const float*)d_in[7];   (void)bq;  // drops out (shift-invariance)
  const float* Wk   = (const float*)d_in[8];
  const float* bk   = (const float*)d_in[9];   (void)bk;  // drops out
  const float* Wv   = (const float*)d_in[10];
  const float* bv   = (const float*)d_in[11];
  const float* Wo   = (const float*)d_in[12];
  const float* bo   = (const float*)d_in[13];
  const float* Wc1  = (const float*)d_in[14];
  const float* bc1  = (const float*)d_in[15];
  const float* Wc2  = (const float*)d_in[16];
  const float* bc2  = (const float*)d_in[17];
  const float* ng   = (const float*)d_in[18];
  const float* nb   = (const float*)d_in[19];
  const float* cw   = (const float*)d_in[20];
  const float* cb   = (const float*)d_in[21];
  const float* bng  = (const float*)d_in[22];
  const float* bnb  = (const float*)d_in[23];
  const float* bnm  = (const float*)d_in[24];
  const float* bnv  = (const float*)d_in[25];
  const float* l1w  = (const float*)d_in[26];
  const float* l1b  = (const float*)d_in[27];
  const float* l2g  = (const float*)d_in[28];
  const float* l2b  = (const float*)d_in[29];
  const float* l2w  = (const float*)d_in[30];
  const float* l2bi = (const float*)d_in[31];
  float* out = (float*)d_out;

  // ---- workspace carve-up ----
  char* wp = (char*)d_ws;
  auto alloc = [&](size_t bytes) { char* p = wp; wp += (bytes + 255) & ~(size_t)255; return p; };
  float*    Xf  = (float*)   alloc(ND_ * 4);
  ushort_t* Xh  = (ushort_t*)alloc(ND_ * 2);
  ushort_t* Xl  = (ushort_t*)alloc(ND_ * 2);
  ushort_t* R1  = (ushort_t*)alloc(ND_ * 2 * 4);   // XMh|XMl ; precompute scratch ; Gh ; F(head)
  float*    Pv  = (float*)   alloc(ND_ * 4);       // P = X*Wvo^T ; head: LN output
  float*    Y   = (float*)   alloc(ND_ * 4);       // residual sums / conv out
  float*    MVP = (float*)   alloc((size_t)B_ * 16 * L_ * 4);
  float*    WT  = (float*)   alloc(B_ * TOPK_ * 4);
  int*      DT  = (int*)     alloc(B_ * TOPK_ * 4);
  float*    HP  = (float*)   alloc(B_ * LATENT_ * 4);
  float*    HH  = (float*)   alloc(B_ * LATENT_ * 4);
  const size_t DD = (size_t)D_ * D_, DF = (size_t)DFF_ * D_;
  ushort_t* MTh  = (ushort_t*)alloc(NL_ * DD * 2);   // (Wk^T Wq) = M^T, hi
  ushort_t* MTl  = (ushort_t*)alloc(NL_ * DD * 2);   // lo
  ushort_t* WvoH = (ushort_t*)alloc(NL_ * DD * 2);   // Wo*Wv, bf16
  float*    BVO  = (float*)   alloc(NL_ * D_ * 4);   // Wo*bv + bo
  ushort_t* W1H  = (ushort_t*)alloc(NL_ * DF * 2);
  ushort_t* W2H  = (ushort_t*)alloc(NL_ * DF * 2);
  ushort_t* WTC  = (ushort_t*)alloc((size_t)CMID_ * 3 * D_ * 2);

  ushort_t* XMh = R1;
  ushort_t* XMl = R1 + ND_;
  ushort_t* Gh  = R1;          // FFN mid, overlays whole R1
  float*    F   = (float*)R1;  // head pooled features
  ushort_t* Sh  = Xh;          // head bf16 plane (X planes dead at head)

  // precompute scratch planes (overlay R1 — dead until the layer loop)
  ushort_t* SC = R1;
  ushort_t* WqTh = SC;             ushort_t* WqTl = SC + 1 * NL_ * DD;
  ushort_t* WkTh = SC + 2 * NL_ * DD; ushort_t* WkTl = SC + 3 * NL_ * DD;
  ushort_t* WvTh = SC + 4 * NL_ * DD; ushort_t* WvTl = SC + 5 * NL_ * DD;
  ushort_t* WoH  = SC + 6 * NL_ * DD; ushort_t* WoL  = SC + 7 * NL_ * DD;

  // ---- precompute: transposed/split weight planes in scratch ----
  tsplit<<<dim3(24, 24, NL_), 256, 0, stream>>>(Wq, WqTh, WqTl);
  tsplit<<<dim3(24, 24, NL_), 256, 0, stream>>>(Wk, WkTh, WkTl);
  tsplit<<<dim3(24, 24, NL_), 256, 0, stream>>>(Wv, WvTh, WvTl);
  wsplit<<<512, 256, 0, stream>>>(Wo, WoH, WoL, NL_ * DD);
  // persistent FFN/conv weights
  wsplit<<<1024, 256, 0, stream>>>(Wc1, W1H, nullptr, NL_ * DF);
  wsplit<<<1024, 256, 0, stream>>>(Wc2, W2H, nullptr, NL_ * DF);
  conv_w_repack<<<(CMID_ * 3 * D_ + 255) / 256, 256, 0, stream>>>(cw, WTC);

  // per-layer fused weights: M^T = Wk^T*Wq (split), Wvo = Wo*Wv (bf16), bvo
  for (int l = 0; l < NL_; l++) {
    gemm_bf16<0, true, 2><<<36, 256, 0, stream>>>(WkTh + l*DD, WkTl + l*DD, WqTh + l*DD, WqTl + l*DD,
                                                  nullptr, nullptr, MTh + l*DD, MTl + l*DD,
                                                  D_, D_, D_, 0, 0, 0, 6, 6);
    gemm_bf16<0, true, 1><<<36, 256, 0, stream>>>(WoH + l*DD, WoL + l*DD, WvTh + l*DD, WvTl + l*DD,
                                                  nullptr, nullptr, WvoH + l*DD, nullptr,
                                                  D_, D_, D_, 0, 0, 0, 6, 6);
    bvo_k<<<3, 256, 0, stream>>>(Wo + l*DD, bv + l*D_, bo + l*D_, BVO + l*D_);
  }

  // ---- embeddings + LN ----
  embed_ln<<<NROWS_, 256, 0, stream>>>(ids, we, pe, te, elng, elnb, Xf, Xh, Xl);

  for (int l = 0; l < NL_; l++) {
    // XM = X * M (split in/out)  [scores = (XM) X^T; Q/K biases drop out of top-k+softmax]
    gemm_bf16<0, true, 2><<<768, 256, 0, stream>>>(Xh, Xl, MTh + l*DD, MTl + l*DD, nullptr, nullptr,
                                                   XMh, XMl, D_, D_, D_, 0, 0, 0, 6, 128);
    // P = X * Wvo^T + bvo   (collapsed V->O projection)
    gemm_bf16<0, false, 0><<<768, 256, 0, stream>>>(Xh, nullptr, WvoH + l*DD, nullptr, BVO + l*D_, nullptr,
                                                    Pv, nullptr, D_, D_, D_, 0, 0, 0, 6, 128);
    // scores -> circular-delay partials (batched, split)
    gemm_bf16<0, true, 3><<<512, 256, 0, stream>>>(XMh, XMl, Xh, Xl, nullptr, nullptr,
                                                   MVP, nullptr, L_, D_, D_,
                                                   (long long)L_ * D_, (long long)L_ * D_, 0, 4, 4);
    topk_softmax<<<B_, 256, 0, stream>>>(MVP, WT, DT);
    // Y = agg(P) + X  (fused residual)
    agg_res<<<NROWS_, 256, 0, stream>>>(Pv, WT, DT, Xf, Y);
    decomp_pl<<<(B_ * 4 * D_) / 256, 256, 0, stream>>>(Y, Xf, Xh, Xl);
    // FFN
    gemm_bf16<1, false, 1><<<3072, 256, 0, stream>>>(Xh, nullptr, W1H + l*DF, nullptr, bc1 + l*DFF_, nullptr,
                                                     Gh, nullptr, DFF_, D_, D_, 0, 0, 0, 24, 128);
    gemm_bf16<0, false, 0><<<768, 256, 0, stream>>>(Gh, nullptr, W2H + l*DF, nullptr, bc2 + l*D_, Xf,
                                                    Y, nullptr, D_, DFF_, DFF_, 0, 0, 0, 6, 128);
    bool last = (l == NL_ - 1);
    decomp_pl<<<(B_ * 4 * D_) / 256, 256, 0, stream>>>(Y, Xf,
                                                       last ? nullptr : Xh, last ? nullptr : Xl);
  }

  // my_Layernorm + column-center, bf16 plane for conv
  ln_rows<<<NROWS_, 256, 0, stream>>>(Xf, Pv, ng, nb, 1e-5f);
  colmean_bf16<<<(B_ * D_ + 255) / 256, 256, 0, stream>>>(Pv, Sh);

  // conv1d as GEMM (lda=768, K=2304, out [b,t,384] fp32 in Y)
  gemm_bf16<0, false, 0><<<384, 256, 0, stream>>>(Sh, nullptr, WTC, nullptr, cb, nullptr,
                                                  Y, nullptr, CMID_, 3 * D_, D_, 0, 0, 0, 3, 128);
  bn_elu_pool<<<(B_ * CMID_ * PLEN_ + 255) / 256, 256, 0, stream>>>(Y, bnm, bnv, bng, bnb, F);
  lin1_k<<<dim3(LATENT_, B_), 256, 0, stream>>>(F, l1w, l1b, HP);
  ln_elu<<<B_, 64, 0, stream>>>(HP, l2g, l2b, HH);
  lin2_sig<<<(B_ * NCELLS_ + 255) / 256, 256, 0, stream>>>(HH, l2w, l2bi, out);
}

// Round 6
// 1247.645 us; speedup vs baseline: 7.4427x; 1.3024x over previous
//
#include <hip/hip_runtime.h>
#include <hip/hip_bf16.h>

#define B_ 32
#define L_ 512
#define D_ 768
#define DFF_ 3072
#define NL_ 2
#define TOPK_ 6
#define CMID_ 384
#define CLEN_ 510
#define PLEN_ 255
#define LATENT_ 32
#define NCELLS_ 2034
#define NROWS_ (B_*L_)
#define ND_ ((size_t)B_*L_*D_)

typedef unsigned short ushort_t;
typedef __attribute__((ext_vector_type(8))) short short8;
typedef __attribute__((ext_vector_type(4))) float f32x4;

typedef const __attribute__((address_space(1))) unsigned int* gp1;
typedef __attribute__((address_space(3))) unsigned int* lp3;

static __device__ __forceinline__ void gload16(const ushort_t* g, ushort_t* l) {
  __builtin_amdgcn_global_load_lds((gp1)g, (lp3)l, 16, 0, 0);
}

static __device__ __forceinline__ float geluf(float x) {
  return 0.5f * x * (1.f + erff(x * 0.70710678118654752440f));
}
static __device__ __forceinline__ float eluf(float x) {
  return x > 0.f ? x : expm1f(x);
}
static __device__ __forceinline__ ushort_t bf16rn(float f) {
  unsigned u = __builtin_bit_cast(unsigned, f);
  u = u + 0x7FFFu + ((u >> 16) & 1u);
  return (ushort_t)(u >> 16);
}
static __device__ __forceinline__ float bf16tof(ushort_t s) {
  unsigned u = ((unsigned)s) << 16;
  return __builtin_bit_cast(float, u);
}
static __device__ __forceinline__ f32x4 mfma16(short8 a, short8 b, f32x4 c) {
  return __builtin_amdgcn_mfma_f32_16x16x32_bf16(a, b, c, 0, 0, 0);
}

// ---------------- weight conversion ----------------
__global__ void wsplit(const float* __restrict__ w, ushort_t* __restrict__ hi,
                       ushort_t* __restrict__ lo, size_t n) {
  size_t stride = (size_t)gridDim.x * blockDim.x;
  for (size_t i = (size_t)blockIdx.x * blockDim.x + threadIdx.x; i < n; i += stride) {
    float v = w[i];
    ushort_t h = bf16rn(v);
    hi[i] = h;
    if (lo) lo[i] = bf16rn(v - bf16tof(h));
  }
}

// transpose + split: hiT[a,j] (+loT) = split(in[j,a]); per-layer via blockIdx.z
__global__ __launch_bounds__(256) void tsplit(const float* __restrict__ in, ushort_t* __restrict__ hiT,
                                              ushort_t* __restrict__ loT) {
  __shared__ float tile[32][33];
  size_t off = (size_t)blockIdx.z * D_ * D_;
  int bx = blockIdx.x * 32, by = blockIdx.y * 32;
  int tx = threadIdx.x & 31, ty = threadIdx.x >> 5;
#pragma unroll
  for (int i = 0; i < 32; i += 8)
    tile[ty + i][tx] = in[off + (size_t)(by + ty + i) * D_ + bx + tx];
  __syncthreads();
#pragma unroll
  for (int i = 0; i < 32; i += 8) {
    float v = tile[tx][ty + i];
    ushort_t h = bf16rn(v);
    size_t o = off + (size_t)(bx + ty + i) * D_ + by + tx;
    hiT[o] = h;
    loT[o] = bf16rn(v - bf16tof(h));
  }
}

// bvo[l,a] = bo[l,a] + sum_j Wo[l,a,j]*bv[l,j]   (batched over layers)
__global__ void bvo_k(const float* __restrict__ wo, const float* __restrict__ bv,
                      const float* __restrict__ bo, float* __restrict__ bvo) {
  int gid = blockIdx.x * 256 + threadIdx.x;
  if (gid >= NL_ * D_) return;
  int l = gid / D_, a = gid % D_;
  const float* w = wo + (size_t)l * D_ * D_ + (size_t)a * D_;
  const float* b = bv + l * D_;
  float s = bo[gid];
  for (int j = 0; j < D_; j++) s = fmaf(w[j], b[j], s);
  bvo[gid] = s;
}

// conv weight repack+convert: wt[o, j*768+i] = bf16(w[o, i, j])
__global__ void conv_w_repack(const float* __restrict__ w, ushort_t* __restrict__ wt) {
  int gid = blockIdx.x * blockDim.x + threadIdx.x;
  if (gid >= CMID_ * 3 * D_) return;
  int o = gid / (3 * D_);
  int k = gid % (3 * D_);
  int j = k / D_, i = k % D_;
  wt[gid] = bf16rn(w[((size_t)o * D_ + i) * 3 + j]);
}

// ---------------- fused embeddings + LN -> bf16 hi/lo planes only ----------------
__global__ __launch_bounds__(256) void embed_ln(const int* __restrict__ ids, const float* __restrict__ we,
                                                const float* __restrict__ pe, const float* __restrict__ te,
                                                const float* __restrict__ g, const float* __restrict__ bta,
                                                ushort_t* __restrict__ xh, ushort_t* __restrict__ xl) {
  int row = blockIdx.x;
  int tid = threadIdx.x;
  int t = row & (L_ - 1);
  int id = ids[row];
  float v[3];
#pragma unroll
  for (int dd = 0; dd < 3; dd++) {
    int c = tid + dd * 256;
    v[dd] = we[(size_t)id * D_ + c] + pe[(size_t)t * D_ + c] + te[c];
  }
  float s = v[0] + v[1] + v[2];
  float sq = v[0]*v[0] + v[1]*v[1] + v[2]*v[2];
  __shared__ float rs[256], rq[256];
  rs[tid] = s; rq[tid] = sq;
  __syncthreads();
  for (int st = 128; st > 0; st >>= 1) {
    if (tid < st) { rs[tid] += rs[tid + st]; rq[tid] += rq[tid + st]; }
    __syncthreads();
  }
  __shared__ float smu, ssc;
  if (tid == 0) {
    float mu = rs[0] * (1.f / D_);
    float var = fmaxf(rq[0] * (1.f / D_) - mu * mu, 0.f);
    smu = mu; ssc = rsqrtf(var + 1e-12f);
  }
  __syncthreads();
  float mu = smu, sc = ssc;
#pragma unroll
  for (int dd = 0; dd < 3; dd++) {
    int c = tid + dd * 256;
    size_t o = (size_t)row * D_ + c;
    float ov = (v[dd] - mu) * sc * g[c] + bta[c];
    ushort_t h = bf16rn(ov);
    xh[o] = h;
    xl[o] = bf16rn(ov - bf16tof(h));
  }
}

// ---------------- LayerNorm (head) from planes ----------------
__global__ __launch_bounds__(256) void ln_pl(const ushort_t* __restrict__ xh, const ushort_t* __restrict__ xl,
                                             float* __restrict__ out,
                                             const float* __restrict__ g, const float* __restrict__ bta,
                                             float eps) {
  int row = blockIdx.x;
  int tid = threadIdx.x;
  size_t base = (size_t)row * D_;
  float v[3];
#pragma unroll
  for (int dd = 0; dd < 3; dd++) {
    size_t o = base + tid + dd * 256;
    v[dd] = bf16tof(xh[o]) + bf16tof(xl[o]);
  }
  float s = v[0] + v[1] + v[2];
  float sq = v[0]*v[0] + v[1]*v[1] + v[2]*v[2];
  __shared__ float rs[256], rq[256];
  rs[tid] = s; rq[tid] = sq;
  __syncthreads();
  for (int st = 128; st > 0; st >>= 1) {
    if (tid < st) { rs[tid] += rs[tid + st]; rq[tid] += rq[tid + st]; }
    __syncthreads();
  }
  __shared__ float smu, ssc;
  if (tid == 0) {
    float mu = rs[0] * (1.f / D_);
    float var = fmaxf(rq[0] * (1.f / D_) - mu * mu, 0.f);
    smu = mu; ssc = rsqrtf(var + eps);
  }
  __syncthreads();
  float mu = smu, sc = ssc;
  float* o = out + base;
#pragma unroll
  for (int dd = 0; dd < 3; dd++) {
    int c = tid + dd * 256;
    o[c] = (v[dd] - mu) * sc * g[c] + bta[c];
  }
}

// ---------------- MFMA GEMM, bf16-plane inputs, global_load_lds staging -------------
// C[m,o] = act(sum_k A[m,k]*W[o,k] + bias[o] [+ Res]); NT; 128x128x64 tile; 4 waves.
// SPLIT: A/W have hi+lo planes, 3-MFMA compensation.
// EPI: 0 = fp32 store (+plane residual), 1 = bf16 store, 2 = bf16 hi+lo store,
//      3 = circular-diag partials, 4 = conv head (BN+ELU+maxpool2 -> F).
template<int ACT, bool SPLIT, int EPI>
__global__ __launch_bounds__(256) void gemm_bf16(
    const ushort_t* __restrict__ Ah, const ushort_t* __restrict__ Al,
    const ushort_t* __restrict__ Wh, const ushort_t* __restrict__ Wl,
    const float* __restrict__ bias,
    const ushort_t* __restrict__ ResH, const ushort_t* __restrict__ ResL,
    void* __restrict__ C0, void* __restrict__ C1,
    const float* __restrict__ bn_m, const float* __restrict__ bn_v,
    const float* __restrict__ bn_g, const float* __restrict__ bn_b,
    int O, int K, int lda,
    long long sA, long long sW, long long sC,
    int nbx, int nby) {
  constexpr int NP = SPLIT ? 2 : 1;
  __shared__ __align__(16) ushort_t AsH[NP][128 * 64];
  __shared__ __align__(16) ushort_t WsH[NP][128 * 64];
  __shared__ float dsum[EPI == 3 ? 512 : 1];

  // block decode: bijective XCD swizzle (m204) + GROUP_M=8 rasterization
  int nwg = gridDim.x;
  int wg = blockIdx.x;
  {
    int qq = nwg >> 3, rr = nwg & 7;
    int xcd = wg & 7, idx = wg >> 3;
    wg = (xcd < rr ? xcd * (qq + 1) : rr * (qq + 1) + (xcd - rr) * qq) + idx;
  }
  int per_b = nbx * nby;
  int bz = wg / per_b;
  int rem = wg - bz * per_b;
  int gsz = nbx * 8;
  int grp = rem / gsz;
  int ing = rem - grp * gsz;
  int by0 = grp * 8;
  int gmx = min(8, nby - by0);
  int by = by0 + (ing % gmx);
  int bx = ing / gmx;

  const ushort_t* Ahb = Ah + (size_t)bz * sA;
  const ushort_t* Alb = SPLIT ? (Al + (size_t)bz * sA) : nullptr;
  const ushort_t* Whb = Wh + (size_t)bz * sW;
  const ushort_t* Wlb = SPLIT ? (Wl + (size_t)bz * sW) : nullptr;

  int m0 = by * 128, o0 = bx * 128;
  int tid = threadIdx.x;
  int wave = tid >> 6, lane = tid & 63;
  int wm = (wave >> 1) * 64, wn = (wave & 1) * 64;
  int lcol = lane & 15, lk = lane >> 4;

  if (EPI == 3) {
    for (int s = tid; s < 512; s += 256) dsum[s] = 0.f;
  }

  f32x4 acc[4][4] = {};

  // staging geometry: per wave, 4 chunks of 1KB; lane l -> row = chunk*8 + (l>>3),
  // LDS slot (l&7); source global k-chunk pre-swizzled: (l&7) ^ (row&7).
  int r8 = lane >> 3;
  int kc = (((lane & 7) ^ r8) << 3);

  // strength-reduced global pointers (+=64 per K-step)
  const ushort_t *gA[4], *gW[4], *gAl[4], *gWl[4];
#pragma unroll
  for (int i = 0; i < 4; i++) {
    int ch = wave * 4 + i;
    int row = ch * 8 + r8;
    size_t oa = (size_t)(m0 + row) * lda + kc;
    size_t ow = (size_t)(o0 + row) * K + kc;
    gA[i] = Ahb + oa; gW[i] = Whb + ow;
    if (SPLIT) { gAl[i] = Alb + oa; gWl[i] = Wlb + ow; }
  }

  for (int k0 = 0; k0 < K; k0 += 64) {
#pragma unroll
    for (int i = 0; i < 4; i++) {
      int ch = wave * 4 + i;
      gload16(gA[i], &AsH[0][ch * 512]); gA[i] += 64;
      gload16(gW[i], &WsH[0][ch * 512]); gW[i] += 64;
      if (SPLIT) {
        gload16(gAl[i], &AsH[1][ch * 512]); gAl[i] += 64;
        gload16(gWl[i], &WsH[1][ch * 512]); gWl[i] += 64;
      }
    }
    __syncthreads();
#pragma unroll
    for (int kk = 0; kk < 2; kk++) {
      int c = kk * 4 + lk;
      short8 ah[4], bh[4], al[4], bl[4];
#pragma unroll
      for (int i = 0; i < 4; i++) {
        int r = wm + i * 16 + lcol;
        int so = r * 64 + ((c ^ (r & 7)) << 3);
        ah[i] = *(const short8*)&AsH[0][so];
        if (SPLIT) al[i] = *(const short8*)&AsH[1][so];
      }
#pragma unroll
      for (int j = 0; j < 4; j++) {
        int r = wn + j * 16 + lcol;
        int so = r * 64 + ((c ^ (r & 7)) << 3);
        bh[j] = *(const short8*)&WsH[0][so];
        if (SPLIT) bl[j] = *(const short8*)&WsH[1][so];
      }
#pragma unroll
      for (int i = 0; i < 4; i++)
#pragma unroll
        for (int j = 0; j < 4; j++) {
          if (SPLIT) {
            acc[i][j] = mfma16(ah[i], bl[j], acc[i][j]);
            acc[i][j] = mfma16(al[i], bh[j], acc[i][j]);
          }
          acc[i][j] = mfma16(ah[i], bh[j], acc[i][j]);
        }
    }
    __syncthreads();
  }

  if (EPI == 3) {
    // pre-reduce 64 acc values into 28 (i-j, r) groups, then LDS atomics
    float pre[7][4] = {};
#pragma unroll
    for (int i = 0; i < 4; i++)
#pragma unroll
      for (int j = 0; j < 4; j++)
#pragma unroll
        for (int r = 0; r < 4; r++)
          pre[i - j + 3][r] += acc[i][j][r];
    int base = (m0 + wm + lk * 4) - (o0 + wn + lcol);
#pragma unroll
    for (int g = 0; g < 7; g++)
#pragma unroll
      for (int r = 0; r < 4; r++)
        atomicAdd(&dsum[(base + 16 * (g - 3) + r) & (L_ - 1)], pre[g][r]);
    __syncthreads();
    float* mvp = (float*)C0;
    int blk = by * nbx + bx;
    for (int s = tid; s < 512; s += 256)
      mvp[((size_t)bz * 16 + blk) * 512 + s] = dsum[s] * (1.f / D_);
  } else if (EPI == 4) {
    // conv head: c = acc + bias; BN; ELU; maxpool over t-pairs; F[b][col][tp]
#pragma unroll
    for (int j = 0; j < 4; j++) {
      int col = o0 + wn + j * 16 + lcol;
      float cbias = bias[col];
      float sc = rsqrtf(bn_v[col] + 1e-5f) * bn_g[col];
      float shf = bn_b[col] - bn_m[col] * sc;
#pragma unroll
      for (int i = 0; i < 4; i++) {
        int rowb = m0 + wm + i * 16 + lk * 4;
        int t = rowb & (L_ - 1);
        int b = rowb >> 9;
#pragma unroll
        for (int p = 0; p < 2; p++) {
          int tt = t + p * 2;
          if (tt >= CLEN_) continue;
          float v0 = eluf((acc[i][j][p * 2]     + cbias) * sc + shf);
          float v1 = eluf((acc[i][j][p * 2 + 1] + cbias) * sc + shf);
          ((float*)C0)[((size_t)b * CMID_ + col) * PLEN_ + (tt >> 1)] = fmaxf(v0, v1);
        }
      }
    }
  } else {
#pragma unroll
    for (int i = 0; i < 4; i++)
#pragma unroll
      for (int j = 0; j < 4; j++) {
        int col = o0 + wn + j * 16 + lcol;
        float bv = bias ? bias[col] : 0.f;
        int rowb = m0 + wm + i * 16 + lk * 4;
#pragma unroll
        for (int r = 0; r < 4; r++) {
          float v = acc[i][j][r] + bv;
          if (ACT == 1) v = geluf(v);
          size_t off = (size_t)bz * sC + (size_t)(rowb + r) * O + col;
          if (EPI == 0) {
            if (ResH) v += bf16tof(ResH[off]) + bf16tof(ResL[off]);
            ((float*)C0)[off] = v;
          }
          if (EPI == 1) ((ushort_t*)C0)[off] = bf16rn(v);
          if (EPI == 2) {
            ushort_t h = bf16rn(v);
            ((ushort_t*)C0)[off] = h;
            ((ushort_t*)C1)[off] = bf16rn(v - bf16tof(h));
          }
        }
      }
  }
}

// ---------------- top-k(6) + softmax over delays (sums 16 partials) ----------------
__global__ __launch_bounds__(256) void topk_softmax(const float* __restrict__ mvp,
                                                    float* __restrict__ wout, int* __restrict__ dout) {
  int b = blockIdx.x, tid = threadIdx.x;
  __shared__ float vals[L_];
  __shared__ float rv[256];
  __shared__ int ri[256];
  __shared__ float wsel[TOPK_];
  __shared__ int dsel[TOPK_];
  float s0 = 0.f, s1 = 0.f;
  for (int p = 0; p < 16; p++) {
    const float* pp = mvp + ((size_t)b * 16 + p) * L_;
    s0 += pp[tid]; s1 += pp[tid + 256];
  }
  vals[tid] = s0; vals[tid + 256] = s1;
  for (int kk = 0; kk < TOPK_; kk++) {
    __syncthreads();
    float v0 = vals[tid], v1 = vals[tid + 256];
    float bvv = v0; int bi = tid;
    if (v1 > v0) { bvv = v1; bi = tid + 256; }
    rv[tid] = bvv; ri[tid] = bi;
    __syncthreads();
    for (int st = 128; st > 0; st >>= 1) {
      if (tid < st) {
        float ov = rv[tid + st]; int oi = ri[tid + st];
        if (ov > rv[tid] || (ov == rv[tid] && oi < ri[tid])) { rv[tid] = ov; ri[tid] = oi; }
      }
      __syncthreads();
    }
    if (tid == 0) { wsel[kk] = rv[0]; dsel[kk] = ri[0]; vals[ri[0]] = -INFINITY; }
  }
  __syncthreads();
  if (tid == 0) {
    float mx = wsel[0];
    for (int i = 1; i < TOPK_; i++) mx = fmaxf(mx, wsel[i]);
    float e[TOPK_]; float sum = 0.f;
    for (int i = 0; i < TOPK_; i++) { e[i] = expf(wsel[i] - mx); sum += e[i]; }
    for (int i = 0; i < TOPK_; i++) { wout[b * TOPK_ + i] = e[i] / sum; dout[b * TOPK_ + i] = dsel[i]; }
  }
}

// y[b,t,d] = sum_k w[b,k] * P[b,(t+delay[b,k])%L,d] + (xh+xl)[b,t,d]
__global__ __launch_bounds__(256) void agg_res(const ushort_t* __restrict__ P, const float* __restrict__ w,
                                               const int* __restrict__ dly,
                                               const ushort_t* __restrict__ xh, const ushort_t* __restrict__ xl,
                                               float* __restrict__ y) {
  int blr = blockIdx.x;      // b*L + t
  int b = blr >> 9, t = blr & 511;
  int tid = threadIdx.x;
  __shared__ float ww[TOPK_];
  __shared__ int rr[TOPK_];
  if (tid < TOPK_) { ww[tid] = w[b * TOPK_ + tid]; rr[tid] = (t + dly[b * TOPK_ + tid]) & (L_ - 1); }
  __syncthreads();
  const ushort_t* pb = P + (size_t)b * L_ * D_;
#pragma unroll
  for (int dd = 0; dd < 3; dd++) {
    int d = tid + dd * 256;
    size_t o = (size_t)blr * D_ + d;
    float s = bf16tof(xh[o]) + bf16tof(xl[o]);
#pragma unroll
    for (int kk = 0; kk < TOPK_; kk++)
      s = fmaf(ww[kk], bf16tof(pb[(size_t)rr[kk] * D_ + d]), s);
    y[o] = s;
  }
}

// race-free decomp: reads fp32 sum S, writes bf16 hi/lo planes only
__global__ void decomp_pl(const float* __restrict__ s,
                          ushort_t* __restrict__ xh, ushort_t* __restrict__ xl) {
  int gid = blockIdx.x * blockDim.x + threadIdx.x;   // B*8*D
  if (gid >= B_ * 8 * D_) return;
  int d = gid % D_;
  int chunk = (gid / D_) & 7;
  int b = gid / (D_ * 8);
  size_t base = (size_t)b * L_ * D_ + d;
  int t0 = chunk * 64;
  float wsum = 0.f;
  for (int u = t0 - 12; u <= t0 + 12; u++) {
    int uc = u < 0 ? 0 : (u > L_ - 1 ? L_ - 1 : u);
    wsum += s[base + (size_t)uc * D_];
  }
  for (int t = t0; t < t0 + 64; t++) {
    size_t o = base + (size_t)t * D_;
    float v = s[o] - wsum * (1.f / 25.f);
    ushort_t h = bf16rn(v);
    xh[o] = h;
    xl[o] = bf16rn(v - bf16tof(h));
    int ua = t + 13 > L_ - 1 ? L_ - 1 : t + 13;
    int ur = t - 12 < 0 ? 0 : t - 12;
    wsum += s[base + (size_t)ua * D_] - s[base + (size_t)ur * D_];
  }
}

// x[b,:,d] -= mean_t; write bf16 plane only
__global__ void colmean_bf16(const float* __restrict__ x, ushort_t* __restrict__ sh) {
  int gid = blockIdx.x * blockDim.x + threadIdx.x;   // B*D
  if (gid >= B_ * D_) return;
  int d = gid % D_, b = gid / D_;
  const float* col = x + (size_t)b * L_ * D_ + d;
  ushort_t* oc = sh + (size_t)b * L_ * D_ + d;
  float s = 0.f;
  for (int t = 0; t < L_; t++) s += col[(size_t)t * D_];
  float mu = s * (1.f / L_);
  for (int t = 0; t < L_; t++) oc[(size_t)t * D_] = bf16rn(col[(size_t)t * D_] - mu);
}

__global__ __launch_bounds__(256) void lin1_k(const float* __restrict__ f, const float* __restrict__ w,
                                              const float* __restrict__ bias, float* __restrict__ out) {
  int o = blockIdx.x, b = blockIdx.y;
  int tid = threadIdx.x;
  const float4* fr = (const float4*)(f + (size_t)b * (CMID_ * PLEN_));
  const float4* wr = (const float4*)(w + (size_t)o * (CMID_ * PLEN_));
  const int n4 = CMID_ * PLEN_ / 4;
  float s = 0.f;
  for (int i = tid; i < n4; i += 256) {
    float4 a = fr[i], ww = wr[i];
    s += a.x * ww.x + a.y * ww.y + a.z * ww.z + a.w * ww.w;
  }
  __shared__ float red[256];
  red[tid] = s;
  __syncthreads();
  for (int st = 128; st > 0; st >>= 1) {
    if (tid < st) red[tid] += red[tid + st];
    __syncthreads();
  }
  if (tid == 0) out[b * LATENT_ + o] = red[0] + bias[o];
}

__global__ void ln_elu(const float* __restrict__ hp, const float* __restrict__ g,
                       const float* __restrict__ bb, float* __restrict__ h) {
  int b = blockIdx.x;
  int tid = threadIdx.x;   // 64
  __shared__ float v[LATENT_];
  __shared__ float mu_s, sc_s;
  if (tid < LATENT_) v[tid] = hp[b * LATENT_ + tid];
  __syncthreads();
  if (tid == 0) {
    float s = 0.f, sq = 0.f;
    for (int i = 0; i < LATENT_; i++) { s += v[i]; sq += v[i] * v[i]; }
    float mu = s * (1.f / LATENT_);
    float var = fmaxf(sq * (1.f / LATENT_) - mu * mu, 0.f);
    mu_s = mu; sc_s = rsqrtf(var + 1e-5f);
  }
  __syncthreads();
  if (tid < LATENT_) h[b * LATENT_ + tid] = eluf((v[tid] - mu_s) * sc_s * g[tid] + bb[tid]);
}

__global__ void lin2_sig(const float* __restrict__ h, const float* __restrict__ w,
                         const float* __restrict__ bias, float* __restrict__ out) {
  int gid = blockIdx.x * blockDim.x + threadIdx.x;
  if (gid >= B_ * NCELLS_) return;
  int b = gid / NCELLS_, c = gid % NCELLS_;
  const float* hr = h + b * LATENT_;
  const float* wr = w + (size_t)c * LATENT_;
  float s = bias[c];
  for (int j = 0; j < LATENT_; j++) s = fmaf(hr[j], wr[j], s);
  out[gid] = 1.f / (1.f + expf(-s));
}

extern "C" void kernel_launch(void* const* d_in, const int* in_sizes, int n_in,
                              void* d_out, int out_size, void* d_ws, size_t ws_size,
                              hipStream_t stream) {
  const int*   ids  = (const int*)  d_in[0];
  const float* we   = (const float*)d_in[1];
  const float* pe   = (const float*)d_in[2];
  const float* te   = (const float*)d_in[3];
  const float* elng = (const float*)d_in[4];
  const float* elnb = (const float*)d_in[5];
  const float* Wq   = (const float*)d_in[6];
  const float* bq   = (const float*)d_in[7];   (void)bq;  // drops out (shift-invariance)
  const float* Wk   = (const float*)d_in[8];
  const float* bk   = (const float*)d_in[9];   (void)bk;  // drops out
  const float* Wv   = (const float*)d_in[10];
  const float* bv   = (const float*)d_in[11];
  const float* Wo   = (const float*)d_in[12];
  const float* bo   = (const float*)d_in[13];
  const float* Wc1  = (const float*)d_in[14];
  const float* bc1  = (const float*)d_in[15];
  const float* Wc2  = (const float*)d_in[16];
  const float* bc2  = (const float*)d_in[17];
  const float* ng   = (const float*)d_in[18];
  const float* nb   = (const float*)d_in[19];
  const float* cw   = (const float*)d_in[20];
  const float* cb   = (const float*)d_in[21];
  const float* bng  = (const float*)d_in[22];
  const float* bnb  = (const float*)d_in[23];
  const float* bnm  = (const float*)d_in[24];
  const float* bnv  = (const float*)d_in[25];
  const float* l1w  = (const float*)d_in[26];
  const float* l1b  = (const float*)d_in[27];
  const float* l2g  = (const float*)d_in[28];
  const float* l2b  = (const float*)d_in[29];
  const float* l2w  = (const float*)d_in[30];
  const float* l2bi = (const float*)d_in[31];
  float* out = (float*)d_out;

  // ---- workspace carve-up ----
  char* wp = (char*)d_ws;
  auto alloc = [&](size_t bytes) { char* p = wp; wp += (bytes + 255) & ~(size_t)255; return p; };
  ushort_t* Xh  = (ushort_t*)alloc(ND_ * 2);
  ushort_t* Xl  = (ushort_t*)alloc(ND_ * 2);
  ushort_t* R1  = (ushort_t*)alloc(ND_ * 2 * 4);   // XMh|XMl ; precompute scratch ; Gh ; F(head)
  char*     PvB = (char*)    alloc(ND_ * 4);       // P bf16 ; head: LN fp32 output
  float*    Y   = (float*)   alloc(ND_ * 4);       // residual sums (fp32)
  float*    MVP = (float*)   alloc((size_t)B_ * 16 * L_ * 4);
  float*    WT  = (float*)   alloc(B_ * TOPK_ * 4);
  int*      DT  = (int*)     alloc(B_ * TOPK_ * 4);
  float*    HP  = (float*)   alloc(B_ * LATENT_ * 4);
  float*    HH  = (float*)   alloc(B_ * LATENT_ * 4);
  const size_t DD = (size_t)D_ * D_, DF = (size_t)DFF_ * D_;
  ushort_t* MTh  = (ushort_t*)alloc(NL_ * DD * 2);   // (Wk^T Wq) = M^T, hi
  ushort_t* MTl  = (ushort_t*)alloc(NL_ * DD * 2);   // lo
  ushort_t* WvoH = (ushort_t*)alloc(NL_ * DD * 2);   // Wo*Wv, bf16
  float*    BVO  = (float*)   alloc(NL_ * D_ * 4);   // Wo*bv + bo
  ushort_t* W1H  = (ushort_t*)alloc(NL_ * DF * 2);
  ushort_t* W2H  = (ushort_t*)alloc(NL_ * DF * 2);
  ushort_t* WTC  = (ushort_t*)alloc((size_t)CMID_ * 3 * D_ * 2);

  ushort_t* XMh = R1;
  ushort_t* XMl = R1 + ND_;
  ushort_t* Gh  = R1;          // FFN mid, overlays whole R1
  float*    F   = (float*)R1;  // head pooled features
  ushort_t* Pb  = (ushort_t*)PvB;   // P bf16
  float*    LNo = (float*)PvB;      // head LN output (P dead)
  ushort_t* Sh  = Xh;               // head bf16 plane

  // precompute scratch planes (overlay R1 — dead until the layer loop)
  ushort_t* SC = R1;
  ushort_t* WqTh = SC;                ushort_t* WqTl = SC + 1 * NL_ * DD;
  ushort_t* WkTh = SC + 2 * NL_ * DD; ushort_t* WkTl = SC + 3 * NL_ * DD;
  ushort_t* WvTh = SC + 4 * NL_ * DD; ushort_t* WvTl = SC + 5 * NL_ * DD;
  ushort_t* WoH  = SC + 6 * NL_ * DD; ushort_t* WoL  = SC + 7 * NL_ * DD;

  // ---- precompute: transposed/split weight planes in scratch ----
  tsplit<<<dim3(24, 24, NL_), 256, 0, stream>>>(Wq, WqTh, WqTl);
  tsplit<<<dim3(24, 24, NL_), 256, 0, stream>>>(Wk, WkTh, WkTl);
  tsplit<<<dim3(24, 24, NL_), 256, 0, stream>>>(Wv, WvTh, WvTl);
  wsplit<<<512, 256, 0, stream>>>(Wo, WoH, WoL, NL_ * DD);
  wsplit<<<1024, 256, 0, stream>>>(Wc1, W1H, nullptr, NL_ * DF);
  wsplit<<<1024, 256, 0, stream>>>(Wc2, W2H, nullptr, NL_ * DF);
  conv_w_repack<<<(CMID_ * 3 * D_ + 255) / 256, 256, 0, stream>>>(cw, WTC);

  // fused weights, batched over layers: M^T = Wk^T*Wq (split), Wvo = Wo*Wv (bf16), bvo
  gemm_bf16<0, true, 2><<<72, 256, 0, stream>>>(WkTh, WkTl, WqTh, WqTl, nullptr, nullptr, nullptr,
                                                MTh, MTl, nullptr, nullptr, nullptr, nullptr,
                                                D_, D_, D_, (long long)DD, (long long)DD, (long long)DD, 6, 6);
  gemm_bf16<0, true, 1><<<72, 256, 0, stream>>>(WoH, WoL, WvTh, WvTl, nullptr, nullptr, nullptr,
                                                WvoH, nullptr, nullptr, nullptr, nullptr, nullptr,
                                                D_, D_, D_, (long long)DD, (long long)DD, (long long)DD, 6, 6);
  bvo_k<<<(NL_ * D_ + 255) / 256, 256, 0, stream>>>(Wo, bv, bo, BVO);

  // ---- embeddings + LN (planes only) ----
  embed_ln<<<NROWS_, 256, 0, stream>>>(ids, we, pe, te, elng, elnb, Xh, Xl);

  for (int l = 0; l < NL_; l++) {
    // XM = X * M (split in/out)
    gemm_bf16<0, true, 2><<<768, 256, 0, stream>>>(Xh, Xl, MTh + l*DD, MTl + l*DD, nullptr, nullptr, nullptr,
                                                   XMh, XMl, nullptr, nullptr, nullptr, nullptr,
                                                   D_, D_, D_, 0, 0, 0, 6, 128);
    // P = X * Wvo^T + bvo -> bf16
    gemm_bf16<0, false, 1><<<768, 256, 0, stream>>>(Xh, nullptr, WvoH + l*DD, nullptr, BVO + l*D_, nullptr, nullptr,
                                                    Pb, nullptr, nullptr, nullptr, nullptr, nullptr,
                                                    D_, D_, D_, 0, 0, 0, 6, 128);
    // scores -> circular-delay partials (batched, split)
    gemm_bf16<0, true, 3><<<512, 256, 0, stream>>>(XMh, XMl, Xh, Xl, nullptr, nullptr, nullptr,
                                                   MVP, nullptr, nullptr, nullptr, nullptr, nullptr,
                                                   L_, D_, D_, (long long)L_ * D_, (long long)L_ * D_, 0, 4, 4);
    topk_softmax<<<B_, 256, 0, stream>>>(MVP, WT, DT);
    // Y = agg(P) + X
    agg_res<<<NROWS_, 256, 0, stream>>>(Pb, WT, DT, Xh, Xl, Y);
    decomp_pl<<<(B_ * 8 * D_) / 256, 256, 0, stream>>>(Y, Xh, Xl);
    // FFN
    gemm_bf16<1, false, 1><<<3072, 256, 0, stream>>>(Xh, nullptr, W1H + l*DF, nullptr, bc1 + l*DFF_, nullptr, nullptr,
                                                     Gh, nullptr, nullptr, nullptr, nullptr, nullptr,
                                                     DFF_, D_, D_, 0, 0, 0, 24, 128);
    gemm_bf16<0, false, 0><<<768, 256, 0, stream>>>(Gh, nullptr, W2H + l*DF, nullptr, bc2 + l*D_, Xh, Xl,
                                                    Y, nullptr, nullptr, nullptr, nullptr, nullptr,
                                                    D_, DFF_, DFF_, 0, 0, 0, 6, 128);
    decomp_pl<<<(B_ * 8 * D_) / 256, 256, 0, stream>>>(Y, Xh, Xl);
  }

  // my_Layernorm + column-center, bf16 plane for conv
  ln_pl<<<NROWS_, 256, 0, stream>>>(Xh, Xl, LNo, ng, nb, 1e-5f);
  colmean_bf16<<<(B_ * D_ + 255) / 256, 256, 0, stream>>>(LNo, Sh);

  // conv1d as GEMM with fused BN+ELU+maxpool epilogue -> F
  gemm_bf16<0, false, 4><<<384, 256, 0, stream>>>(Sh, nullptr, WTC, nullptr, cb, nullptr, nullptr,
                                                  F, nullptr, bnm, bnv, bng, bnb,
                                                  CMID_, 3 * D_, D_, 0, 0, 0, 3, 128);
  lin1_k<<<dim3(LATENT_, B_), 256, 0, stream>>>(F, l1w, l1b, HP);
  ln_elu<<<B_, 64, 0, stream>>>(HP, l2g, l2b, HH);
  lin2_sig<<<(B_ * NCELLS_ + 255) / 256, 256, 0, stream>>>(HH, l2w, l2bi, out);
}